// Round 1
// baseline (718.603 us; speedup 1.0000x reference)
//
#include <hip/hip_runtime.h>

#define B_ 2
#define S_ 2048
#define D_ 2048
#define H_ 32
#define KV_ 8
#define HD_ 64

typedef unsigned short bf16_t;
typedef __attribute__((ext_vector_type(8))) short short8;
typedef __attribute__((ext_vector_type(4))) float floatx4;

__device__ __forceinline__ bf16_t f2bf(float f) {
  union { float f; unsigned u; } c; c.f = f;
  unsigned u = c.u;
  u += 0x7fffu + ((u >> 16) & 1u);          // round-to-nearest-even
  return (bf16_t)(u >> 16);
}

__device__ __forceinline__ void load_lds16(const void* g, void* l) {
  __builtin_amdgcn_global_load_lds(
      (const __attribute__((address_space(1))) void*)g,
      (__attribute__((address_space(3))) void*)l, 16, 0, 0);
}

// ---------------- fp32 -> bf16 convert (vectorized x4) ----------------
__global__ __launch_bounds__(256) void cvt_bf16(const float* __restrict__ in,
                                                bf16_t* __restrict__ out, int n4) {
  int i = blockIdx.x * 256 + threadIdx.x;
  if (i >= n4) return;
  float4 v = ((const float4*)in)[i];
  ushort4 o;
  o.x = f2bf(v.x); o.y = f2bf(v.y); o.z = f2bf(v.z); o.w = f2bf(v.w);
  ((ushort4*)out)[i] = o;
}

// ---------------- bf16 GEMM: C[M,N] = A[M,K] * B^T, B given [N,K] ----------------
// m97 structure: 128x128 tile, BK=32, 4 waves of 64x64, global_load_lds width 16.
__global__ __launch_bounds__(256) void gemm_bt(
    const bf16_t* __restrict__ A, const bf16_t* __restrict__ Bm,
    float* __restrict__ C, int M, int N, int K) {
  __shared__ __attribute__((aligned(16))) bf16_t As[128 * 32];
  __shared__ __attribute__((aligned(16))) bf16_t Bs[128 * 32];
  const int tid = threadIdx.x;
  const int lane = tid & 63;
  const int wave = tid >> 6;
  const int bm = blockIdx.y * 128, bn = blockIdx.x * 128;
  const int wm = (wave >> 1) * 64, wn = (wave & 1) * 64;
  const int lr = lane & 15, quad = lane >> 4;

  floatx4 acc[4][4] = {};

  const int t0 = tid, t1 = tid + 256;          // 16B-unit indices into the tile
  const int r0 = t0 >> 2, c0 = (t0 & 3) * 8;   // row / bf16-elem col within tile
  const int r1 = t1 >> 2, c1 = (t1 & 3) * 8;

  const bf16_t* Ab = A + (size_t)bm * K;
  const bf16_t* Bb = Bm + (size_t)bn * K;

  for (int k0 = 0; k0 < K; k0 += 32) {
    __syncthreads();
    load_lds16(Ab + (size_t)r0 * K + k0 + c0, &As[t0 * 8]);
    load_lds16(Ab + (size_t)r1 * K + k0 + c1, &As[t1 * 8]);
    load_lds16(Bb + (size_t)r0 * K + k0 + c0, &Bs[t0 * 8]);
    load_lds16(Bb + (size_t)r1 * K + k0 + c1, &Bs[t1 * 8]);
    __syncthreads();

    short8 af[4], bfr[4];
#pragma unroll
    for (int i = 0; i < 4; i++) {
      af[i]  = *(const short8*)&As[(wm + i * 16 + lr) * 32 + quad * 8];
      bfr[i] = *(const short8*)&Bs[(wn + i * 16 + lr) * 32 + quad * 8];
    }
#pragma unroll
    for (int mi = 0; mi < 4; mi++)
#pragma unroll
      for (int ni = 0; ni < 4; ni++)
        acc[mi][ni] = __builtin_amdgcn_mfma_f32_16x16x32_bf16(af[mi], bfr[ni], acc[mi][ni], 0, 0, 0);
  }

#pragma unroll
  for (int mi = 0; mi < 4; mi++) {
    const int row = bm + wm + mi * 16 + quad * 4;
#pragma unroll
    for (int ni = 0; ni < 4; ni++) {
      const int col = bn + wn + ni * 16 + lr;
      float* cp = C + (size_t)row * N + col;
#pragma unroll
      for (int r = 0; r < 4; r++) cp[(size_t)r * N] = acc[mi][ni][r];
    }
  }
}

// ---------------- RoPE + repack ----------------
// qkv [B*S, 3072] fp32 -> Q [B,H,S,64] bf16 (roped), K [B,KV,S,64] bf16 (roped),
// Vt [B,KV,64,S] bf16 (transposed, no rope)
__global__ __launch_bounds__(256) void rope_repack(
    const float* __restrict__ qkv, const float* __restrict__ cs,
    const float* __restrict__ sn, bf16_t* __restrict__ q,
    bf16_t* __restrict__ k, bf16_t* __restrict__ vt) {
  const int bs = blockIdx.x;
  const int b = bs >> 11, s = bs & 2047;
  const float* row = qkv + (size_t)bs * 3072;
  const int tid = threadIdx.x;
  for (int i = tid; i < 2048; i += 256) {
    int hh = i >> 6, d = i & 63;
    float c = cs[s * 64 + d], si = sn[s * 64 + d];
    float t = row[i];
    float other = row[(i & ~63) | ((d + 32) & 63)];
    float rot = (d < 32) ? -other : other;
    q[((size_t)(b * H_ + hh) * S_ + s) * HD_ + d] = f2bf(t * c + rot * si);
  }
  for (int i = tid; i < 512; i += 256) {
    int hh = i >> 6, d = i & 63;
    float c = cs[s * 64 + d], si = sn[s * 64 + d];
    float t = row[2048 + i];
    float other = row[2048 + ((i & ~63) | ((d + 32) & 63))];
    float rot = (d < 32) ? -other : other;
    k[((size_t)(b * KV_ + hh) * S_ + s) * HD_ + d] = f2bf(t * c + rot * si);
  }
  for (int i = tid; i < 512; i += 256) {
    int hh = i >> 6, d = i & 63;
    vt[((size_t)(b * KV_ + hh) * HD_ + d) * S_ + s] = f2bf(row[2560 + i]);
  }
}

// ---------------- flash attention (causal, GQA 4:1) ----------------
// grid (S/64, B*H); 4 waves/block, each wave owns 16 q-rows independently.
__global__ __launch_bounds__(256) void flash_attn(
    const bf16_t* __restrict__ Q,   // [B*H, S, 64]
    const bf16_t* __restrict__ Kc,  // [B*KV, S, 64]
    const bf16_t* __restrict__ Vt,  // [B*KV, 64, S]
    bf16_t* __restrict__ O) {       // [B, S, H*64]
  __shared__ __attribute__((aligned(16))) bf16_t Pl[4][16 * 40];  // stride 40: 2-way bank alias (free)
  const int bh = blockIdx.y;
  const int b = bh >> 5, h = bh & 31;
  const int kvh = b * KV_ + (h >> 2);
  const int wave = threadIdx.x >> 6, lane = threadIdx.x & 63;
  const int lr = lane & 15, quad = lane >> 4;
  const int q0 = blockIdx.x * 64 + wave * 16;

  const bf16_t* qp = Q + ((size_t)bh * S_ + q0) * HD_;
  const short8 qf0 = *(const short8*)(qp + lr * HD_ + quad * 8);
  const short8 qf1 = *(const short8*)(qp + lr * HD_ + 32 + quad * 8);

  floatx4 o[4] = {};
  float m_r[4], l_r[4];
#pragma unroll
  for (int r = 0; r < 4; r++) { m_r[r] = -1e30f; l_r[r] = 0.f; }

  const bf16_t* kb = Kc + (size_t)kvh * S_ * HD_;
  const bf16_t* vb = Vt + (size_t)kvh * HD_ * S_;
  bf16_t* pl = Pl[wave];

  const int ktiles = (q0 + 15) / 32 + 1;
  for (int kt = 0; kt < ktiles; kt++) {
    const int kk = kt * 32;
    floatx4 s0 = {}, s1 = {};
    short8 kf;
    kf = *(const short8*)(kb + (size_t)(kk + lr) * HD_ + quad * 8);
    s0 = __builtin_amdgcn_mfma_f32_16x16x32_bf16(qf0, kf, s0, 0, 0, 0);
    kf = *(const short8*)(kb + (size_t)(kk + lr) * HD_ + 32 + quad * 8);
    s0 = __builtin_amdgcn_mfma_f32_16x16x32_bf16(qf1, kf, s0, 0, 0, 0);
    kf = *(const short8*)(kb + (size_t)(kk + 16 + lr) * HD_ + quad * 8);
    s1 = __builtin_amdgcn_mfma_f32_16x16x32_bf16(qf0, kf, s1, 0, 0, 0);
    kf = *(const short8*)(kb + (size_t)(kk + 16 + lr) * HD_ + 32 + quad * 8);
    s1 = __builtin_amdgcn_mfma_f32_16x16x32_bf16(qf1, kf, s1, 0, 0, 0);

    const int col0 = kk + lr, col1 = kk + 16 + lr;
    float alpha[4];
#pragma unroll
    for (int r = 0; r < 4; r++) {
      const int rowg = q0 + quad * 4 + r;
      float v0 = (col0 <= rowg) ? s0[r] * 0.125f : -1e30f;
      float v1 = (col1 <= rowg) ? s1[r] * 0.125f : -1e30f;
      float mx = fmaxf(v0, v1);
#pragma unroll
      for (int off = 8; off >= 1; off >>= 1) mx = fmaxf(mx, __shfl_xor(mx, off, 16));
      const float mn = fmaxf(m_r[r], mx);
      const float p0 = __expf(v0 - mn);
      const float p1 = __expf(v1 - mn);
      float rs = p0 + p1;
#pragma unroll
      for (int off = 8; off >= 1; off >>= 1) rs += __shfl_xor(rs, off, 16);
      alpha[r] = __expf(m_r[r] - mn);
      l_r[r] = l_r[r] * alpha[r] + rs;
      m_r[r] = mn;
      pl[(quad * 4 + r) * 40 + lr] = f2bf(p0);
      pl[(quad * 4 + r) * 40 + 16 + lr] = f2bf(p1);
    }
#pragma unroll
    for (int ni = 0; ni < 4; ni++)
#pragma unroll
      for (int r = 0; r < 4; r++) o[ni][r] *= alpha[r];

    __builtin_amdgcn_s_waitcnt(0);  // same-wave ds_write -> ds_read visibility
    const short8 pf = *(const short8*)&pl[lr * 40 + quad * 8];
#pragma unroll
    for (int ni = 0; ni < 4; ni++) {
      short8 vf = *(const short8*)(vb + (size_t)(ni * 16 + lr) * S_ + kk + quad * 8);
      o[ni] = __builtin_amdgcn_mfma_f32_16x16x32_bf16(pf, vf, o[ni], 0, 0, 0);
    }
  }

  float inv_l[4];
#pragma unroll
  for (int r = 0; r < 4; r++) inv_l[r] = 1.f / l_r[r];
  bf16_t* ob = O + ((size_t)b * S_ + q0 + quad * 4) * (H_ * HD_) + h * HD_ + lr;
#pragma unroll
  for (int ni = 0; ni < 4; ni++)
#pragma unroll
    for (int r = 0; r < 4; r++)
      ob[(size_t)r * (H_ * HD_) + ni * 16] = f2bf(o[ni][r] * inv_l[r]);
}

extern "C" void kernel_launch(void* const* d_in, const int* in_sizes, int n_in,
                              void* d_out, int out_size, void* d_ws, size_t ws_size,
                              hipStream_t stream) {
  const float* x    = (const float*)d_in[0];
  const float* cs   = (const float*)d_in[1];
  const float* sn   = (const float*)d_in[2];
  const float* wqkv = (const float*)d_in[3];
  const float* wout = (const float*)d_in[4];
  float* out = (float*)d_out;

  char* ws = (char*)d_ws;
  bf16_t* xb    = (bf16_t*)(ws);                 // 16,777,216 B
  bf16_t* wqkvb = (bf16_t*)(ws + 16777216);      // 12,582,912 B
  bf16_t* woutb = (bf16_t*)(ws + 29360128);      //  8,388,608 B
  float*  qkv   = (float*)(ws + 37748736);       // 50,331,648 B
  bf16_t* qb    = (bf16_t*)(ws + 88080384);      // 16,777,216 B
  bf16_t* kb    = (bf16_t*)(ws + 104857600);     //  4,194,304 B
  bf16_t* vtb   = (bf16_t*)(ws + 109051904);     //  4,194,304 B
  bf16_t* attnb = (bf16_t*)(ws + 113246208);     // 16,777,216 B  (total ~124 MB)

  cvt_bf16<<<8192, 256, 0, stream>>>(x, xb, 2097152);
  cvt_bf16<<<6144, 256, 0, stream>>>(wqkv, wqkvb, 1572864);
  cvt_bf16<<<4096, 256, 0, stream>>>(wout, woutb, 1048576);
  gemm_bt<<<dim3(24, 32), 256, 0, stream>>>(xb, wqkvb, qkv, 4096, 3072, 2048);
  rope_repack<<<4096, 256, 0, stream>>>(qkv, cs, sn, qb, kb, vtb);
  flash_attn<<<dim3(32, 64), 256, 0, stream>>>(qb, kb, vtb, attnb);
  gemm_bt<<<dim3(16, 32), 256, 0, stream>>>(attnb, woutb, out, 4096, 2048, 2048);
}

// Round 2
// 509.350 us; speedup vs baseline: 1.4108x; 1.4108x over previous
//
#include <hip/hip_runtime.h>

#define B_ 2
#define S_ 2048
#define D_ 2048
#define H_ 32
#define KV_ 8
#define HD_ 64

typedef unsigned short bf16_t;
typedef __attribute__((ext_vector_type(8))) short short8;
typedef __attribute__((ext_vector_type(4))) float floatx4;

__device__ __forceinline__ bf16_t f2bf(float f) {
  union { float f; unsigned u; } c; c.f = f;
  unsigned u = c.u;
  u += 0x7fffu + ((u >> 16) & 1u);          // round-to-nearest-even
  return (bf16_t)(u >> 16);
}

__device__ __forceinline__ void load_lds16(const void* g, void* l) {
  __builtin_amdgcn_global_load_lds(
      (const __attribute__((address_space(1))) void*)g,
      (__attribute__((address_space(3))) void*)l, 16, 0, 0);
}

// ---------------- fp32 -> bf16 convert (vectorized x4) ----------------
__global__ __launch_bounds__(256) void cvt_bf16(const float* __restrict__ in,
                                                bf16_t* __restrict__ out, int n4) {
  int i = blockIdx.x * 256 + threadIdx.x;
  if (i >= n4) return;
  float4 v = ((const float4*)in)[i];
  ushort4 o;
  o.x = f2bf(v.x); o.y = f2bf(v.y); o.z = f2bf(v.z); o.w = f2bf(v.w);
  ((ushort4*)out)[i] = o;
}

// ---------------- bf16 GEMM: C[M,N] = A[M,K] * B^T, B given [N,K] ----------------
__global__ __launch_bounds__(256) void gemm_bt(
    const bf16_t* __restrict__ A, const bf16_t* __restrict__ Bm,
    float* __restrict__ C, int M, int N, int K) {
  __shared__ __attribute__((aligned(16))) bf16_t As[128 * 32];
  __shared__ __attribute__((aligned(16))) bf16_t Bs[128 * 32];
  const int tid = threadIdx.x;
  const int lane = tid & 63;
  const int wave = tid >> 6;
  const int bm = blockIdx.y * 128, bn = blockIdx.x * 128;
  const int wm = (wave >> 1) * 64, wn = (wave & 1) * 64;
  const int lr = lane & 15, quad = lane >> 4;

  floatx4 acc[4][4] = {};

  const int t0 = tid, t1 = tid + 256;
  const int r0 = t0 >> 2, c0 = (t0 & 3) * 8;
  const int r1 = t1 >> 2, c1 = (t1 & 3) * 8;

  const bf16_t* Ab = A + (size_t)bm * K;
  const bf16_t* Bb = Bm + (size_t)bn * K;

  for (int k0 = 0; k0 < K; k0 += 32) {
    __syncthreads();
    load_lds16(Ab + (size_t)r0 * K + k0 + c0, &As[t0 * 8]);
    load_lds16(Ab + (size_t)r1 * K + k0 + c1, &As[t1 * 8]);
    load_lds16(Bb + (size_t)r0 * K + k0 + c0, &Bs[t0 * 8]);
    load_lds16(Bb + (size_t)r1 * K + k0 + c1, &Bs[t1 * 8]);
    __syncthreads();

    short8 af[4], bfr[4];
#pragma unroll
    for (int i = 0; i < 4; i++) {
      af[i]  = *(const short8*)&As[(wm + i * 16 + lr) * 32 + quad * 8];
      bfr[i] = *(const short8*)&Bs[(wn + i * 16 + lr) * 32 + quad * 8];
    }
#pragma unroll
    for (int mi = 0; mi < 4; mi++)
#pragma unroll
      for (int ni = 0; ni < 4; ni++)
        acc[mi][ni] = __builtin_amdgcn_mfma_f32_16x16x32_bf16(af[mi], bfr[ni], acc[mi][ni], 0, 0, 0);
  }

#pragma unroll
  for (int mi = 0; mi < 4; mi++) {
    const int row = bm + wm + mi * 16 + quad * 4;
#pragma unroll
    for (int ni = 0; ni < 4; ni++) {
      const int col = bn + wn + ni * 16 + lr;
      float* cp = C + (size_t)row * N + col;
#pragma unroll
      for (int r = 0; r < 4; r++) cp[(size_t)r * N] = acc[mi][ni][r];
    }
  }
}

// ---------------- RoPE + repack ----------------
__global__ __launch_bounds__(256) void rope_repack(
    const float* __restrict__ qkv, const float* __restrict__ cs,
    const float* __restrict__ sn, bf16_t* __restrict__ q,
    bf16_t* __restrict__ k, bf16_t* __restrict__ vt) {
  const int bs = blockIdx.x;
  const int b = bs >> 11, s = bs & 2047;
  const float* row = qkv + (size_t)bs * 3072;
  const int tid = threadIdx.x;
  for (int i = tid; i < 2048; i += 256) {
    int hh = i >> 6, d = i & 63;
    float c = cs[s * 64 + d], si = sn[s * 64 + d];
    float t = row[i];
    float other = row[(i & ~63) | ((d + 32) & 63)];
    float rot = (d < 32) ? -other : other;
    q[((size_t)(b * H_ + hh) * S_ + s) * HD_ + d] = f2bf(t * c + rot * si);
  }
  for (int i = tid; i < 512; i += 256) {
    int hh = i >> 6, d = i & 63;
    float c = cs[s * 64 + d], si = sn[s * 64 + d];
    float t = row[2048 + i];
    float other = row[2048 + ((i & ~63) | ((d + 32) & 63))];
    float rot = (d < 32) ? -other : other;
    k[((size_t)(b * KV_ + hh) * S_ + s) * HD_ + d] = f2bf(t * c + rot * si);
  }
  for (int i = tid; i < 512; i += 256) {
    int hh = i >> 6, d = i & 63;
    vt[((size_t)(b * KV_ + hh) * HD_ + d) * S_ + s] = f2bf(row[2560 + i]);
  }
}

// ---------------- flash attention (causal, GQA 4:1), S^T formulation ----------------
// Scores computed transposed: st = mfma(K_frag, Q_frag) -> C layout col=lane&15=q,
// row=quad*4+r=k. Softmax reduction over k = 15 in-lane ops + 2 shfl (xor16, xor32).
// Bc=64 keys/iter. Each block does q-tiles {blockIdx.x, 31-blockIdx.x} (uniform work).
__device__ __forceinline__ void attn_qblock(
    const bf16_t* __restrict__ Q, const bf16_t* __restrict__ kb,
    const bf16_t* __restrict__ vb, bf16_t* __restrict__ O,
    bf16_t* __restrict__ pl, int bh, int q0, int lr, int quad) {
  const int b = bh >> 5, h = bh & 31;
  const bf16_t* qp = Q + ((size_t)bh * S_ + q0) * HD_;
  const short8 qf0 = *(const short8*)(qp + lr * HD_ + quad * 8);
  const short8 qf1 = *(const short8*)(qp + lr * HD_ + 32 + quad * 8);

  floatx4 o[4] = {};
  float m = -1e30f, l = 0.f;
  const int qg = q0 + lr;           // this lane's q column in score tiles
  const int kend = q0 + 16;

  for (int kk = 0; kk < kend; kk += 64) {
    floatx4 st[4] = {};
#pragma unroll
    for (int t = 0; t < 4; t++) {
      const bf16_t* kp = kb + (size_t)(kk + t * 16 + lr) * HD_;
      short8 kf0 = *(const short8*)(kp + quad * 8);
      short8 kf1 = *(const short8*)(kp + 32 + quad * 8);
      st[t] = __builtin_amdgcn_mfma_f32_16x16x32_bf16(kf0, qf0, st[t], 0, 0, 0);
      st[t] = __builtin_amdgcn_mfma_f32_16x16x32_bf16(kf1, qf1, st[t], 0, 0, 0);
    }
    // mask + scale; element (t,r): k = kk + t*16 + quad*4 + r, q = qg
    float mx = -1e30f;
#pragma unroll
    for (int t = 0; t < 4; t++)
#pragma unroll
      for (int r = 0; r < 4; r++) {
        const int kg = kk + t * 16 + quad * 4 + r;
        const float v = (kg <= qg) ? st[t][r] * 0.125f : -1e30f;
        st[t][r] = v;
        mx = fmaxf(mx, v);
      }
    mx = fmaxf(mx, __shfl_xor(mx, 16, 64));
    mx = fmaxf(mx, __shfl_xor(mx, 32, 64));
    const float mn = fmaxf(m, mx);
    float rs = 0.f;
#pragma unroll
    for (int t = 0; t < 4; t++)
#pragma unroll
      for (int r = 0; r < 4; r++) {
        const float p = __expf(st[t][r] - mn);
        st[t][r] = p;
        rs += p;
      }
    rs += __shfl_xor(rs, 16, 64);
    rs += __shfl_xor(rs, 32, 64);
    const float alpha = __expf(m - mn);
    l = l * alpha + rs;
    m = mn;
    // rescale O: row r of O-tile is q-row quad*4+r; alpha for that q sits in lane q
#pragma unroll
    for (int r = 0; r < 4; r++) {
      const float ar = __shfl(alpha, quad * 4 + r, 16);
#pragma unroll
      for (int dt = 0; dt < 4; dt++) o[dt][r] *= ar;
    }
    // write P^T -> LDS as P[q][k] rows (lane: q=lr fixed, 4 consecutive k per b64)
#pragma unroll
    for (int t = 0; t < 4; t++) {
      ushort4 pk;
      pk.x = f2bf(st[t][0]); pk.y = f2bf(st[t][1]);
      pk.z = f2bf(st[t][2]); pk.w = f2bf(st[t][3]);
      *(ushort4*)&pl[lr * 72 + t * 16 + quad * 4] = pk;
    }
    // read P A-fragment (compiler inserts lgkmcnt-only wait; vm prefetches stay live)
    const short8 pf0 = *(const short8*)&pl[lr * 72 + quad * 8];
    const short8 pf1 = *(const short8*)&pl[lr * 72 + 32 + quad * 8];
#pragma unroll
    for (int dt = 0; dt < 4; dt++) {
      const bf16_t* vp = vb + (size_t)(dt * 16 + lr) * S_ + kk;
      short8 vf0 = *(const short8*)(vp + quad * 8);
      short8 vf1 = *(const short8*)(vp + 32 + quad * 8);
      o[dt] = __builtin_amdgcn_mfma_f32_16x16x32_bf16(pf0, vf0, o[dt], 0, 0, 0);
      o[dt] = __builtin_amdgcn_mfma_f32_16x16x32_bf16(pf1, vf1, o[dt], 0, 0, 0);
    }
  }

  float linv[4];
#pragma unroll
  for (int r = 0; r < 4; r++) linv[r] = 1.f / __shfl(l, quad * 4 + r, 16);
  bf16_t* ob = O + ((size_t)b * S_ + q0 + quad * 4) * (H_ * HD_) + h * HD_ + lr;
#pragma unroll
  for (int dt = 0; dt < 4; dt++)
#pragma unroll
    for (int r = 0; r < 4; r++)
      ob[(size_t)r * (H_ * HD_) + dt * 16] = f2bf(o[dt][r] * linv[r]);
}

__global__ __launch_bounds__(256, 4) void flash_attn(
    const bf16_t* __restrict__ Q,   // [B*H, S, 64]
    const bf16_t* __restrict__ Kc,  // [B*KV, S, 64]
    const bf16_t* __restrict__ Vt,  // [B*KV, 64, S]
    bf16_t* __restrict__ O) {       // [B, S, H*64]
  __shared__ __attribute__((aligned(16))) bf16_t Pl[4][16 * 72];
  const int bh = blockIdx.y;
  const int b = bh >> 5, h = bh & 31;
  const int kvh = b * KV_ + (h >> 2);
  const int wave = threadIdx.x >> 6, lane = threadIdx.x & 63;
  const int lr = lane & 15, quad = lane >> 4;

  const bf16_t* kb = Kc + (size_t)kvh * S_ * HD_;
  const bf16_t* vb = Vt + (size_t)kvh * HD_ * S_;
  bf16_t* pl = Pl[wave];

  const int ta = blockIdx.x;        // light tile
  const int tb = 31 - blockIdx.x;   // heavy tile (combined work uniform)
  attn_qblock(Q, kb, vb, O, pl, bh, ta * 64 + wave * 16, lr, quad);
  attn_qblock(Q, kb, vb, O, pl, bh, tb * 64 + wave * 16, lr, quad);
}

extern "C" void kernel_launch(void* const* d_in, const int* in_sizes, int n_in,
                              void* d_out, int out_size, void* d_ws, size_t ws_size,
                              hipStream_t stream) {
  const float* x    = (const float*)d_in[0];
  const float* cs   = (const float*)d_in[1];
  const float* sn   = (const float*)d_in[2];
  const float* wqkv = (const float*)d_in[3];
  const float* wout = (const float*)d_in[4];
  float* out = (float*)d_out;

  char* ws = (char*)d_ws;
  bf16_t* xb    = (bf16_t*)(ws);                 // 16,777,216 B
  bf16_t* wqkvb = (bf16_t*)(ws + 16777216);      // 12,582,912 B
  bf16_t* woutb = (bf16_t*)(ws + 29360128);      //  8,388,608 B
  float*  qkv   = (float*)(ws + 37748736);       // 50,331,648 B
  bf16_t* qb    = (bf16_t*)(ws + 88080384);      // 16,777,216 B
  bf16_t* kb    = (bf16_t*)(ws + 104857600);     //  4,194,304 B
  bf16_t* vtb   = (bf16_t*)(ws + 109051904);     //  4,194,304 B
  bf16_t* attnb = (bf16_t*)(ws + 113246208);     // 16,777,216 B

  cvt_bf16<<<8192, 256, 0, stream>>>(x, xb, 2097152);
  cvt_bf16<<<6144, 256, 0, stream>>>(wqkv, wqkvb, 1572864);
  cvt_bf16<<<4096, 256, 0, stream>>>(wout, woutb, 1048576);
  gemm_bt<<<dim3(24, 32), 256, 0, stream>>>(xb, wqkvb, qkv, 4096, 3072, 2048);
  rope_repack<<<4096, 256, 0, stream>>>(qkv, cs, sn, qb, kb, vtb);
  flash_attn<<<dim3(16, 64), 256, 0, stream>>>(qb, kb, vtb, attnb);
  gemm_bt<<<dim3(16, 32), 256, 0, stream>>>(attnb, woutb, out, 4096, 2048, 2048);
}

// Round 3
// 374.375 us; speedup vs baseline: 1.9195x; 1.3605x over previous
//
#include <hip/hip_runtime.h>

#define B_ 2
#define S_ 2048
#define D_ 2048
#define H_ 32
#define KV_ 8
#define HD_ 64

typedef unsigned short bf16_t;
typedef __attribute__((ext_vector_type(8))) short short8;
typedef __attribute__((ext_vector_type(4))) float floatx4;

__device__ __forceinline__ bf16_t f2bf(float f) {
  union { float f; unsigned u; } c; c.f = f;
  unsigned u = c.u;
  u += 0x7fffu + ((u >> 16) & 1u);          // round-to-nearest-even
  return (bf16_t)(u >> 16);
}

__device__ __forceinline__ void load_lds16(const void* g, void* l) {
  __builtin_amdgcn_global_load_lds(
      (const __attribute__((address_space(1))) void*)g,
      (__attribute__((address_space(3))) void*)l, 16, 0, 0);
}

// ---------------- fp32 -> bf16 convert (vectorized x4) ----------------
__global__ __launch_bounds__(256) void cvt_bf16(const float* __restrict__ in,
                                                bf16_t* __restrict__ out, int n4) {
  int i = blockIdx.x * 256 + threadIdx.x;
  if (i >= n4) return;
  float4 v = ((const float4*)in)[i];
  ushort4 o;
  o.x = f2bf(v.x); o.y = f2bf(v.y); o.z = f2bf(v.z); o.w = f2bf(v.w);
  ((ushort4*)out)[i] = o;
}

// ---------------- bf16 GEMM: C[M,N] = A[M,K] * B^T, B given [N,K] ----------------
__global__ __launch_bounds__(256) void gemm_bt(
    const bf16_t* __restrict__ A, const bf16_t* __restrict__ Bm,
    float* __restrict__ C, int M, int N, int K) {
  __shared__ __attribute__((aligned(16))) bf16_t As[128 * 32];
  __shared__ __attribute__((aligned(16))) bf16_t Bs[128 * 32];
  const int tid = threadIdx.x;
  const int lane = tid & 63;
  const int wave = tid >> 6;
  const int bm = blockIdx.y * 128, bn = blockIdx.x * 128;
  const int wm = (wave >> 1) * 64, wn = (wave & 1) * 64;
  const int lr = lane & 15, quad = lane >> 4;

  floatx4 acc[4][4] = {};

  const int t0 = tid, t1 = tid + 256;
  const int r0 = t0 >> 2, c0 = (t0 & 3) * 8;
  const int r1 = t1 >> 2, c1 = (t1 & 3) * 8;

  const bf16_t* Ab = A + (size_t)bm * K;
  const bf16_t* Bb = Bm + (size_t)bn * K;

  for (int k0 = 0; k0 < K; k0 += 32) {
    __syncthreads();
    load_lds16(Ab + (size_t)r0 * K + k0 + c0, &As[t0 * 8]);
    load_lds16(Ab + (size_t)r1 * K + k0 + c1, &As[t1 * 8]);
    load_lds16(Bb + (size_t)r0 * K + k0 + c0, &Bs[t0 * 8]);
    load_lds16(Bb + (size_t)r1 * K + k0 + c1, &Bs[t1 * 8]);
    __syncthreads();

    short8 af[4], bfr[4];
#pragma unroll
    for (int i = 0; i < 4; i++) {
      af[i]  = *(const short8*)&As[(wm + i * 16 + lr) * 32 + quad * 8];
      bfr[i] = *(const short8*)&Bs[(wn + i * 16 + lr) * 32 + quad * 8];
    }
#pragma unroll
    for (int mi = 0; mi < 4; mi++)
#pragma unroll
      for (int ni = 0; ni < 4; ni++)
        acc[mi][ni] = __builtin_amdgcn_mfma_f32_16x16x32_bf16(af[mi], bfr[ni], acc[mi][ni], 0, 0, 0);
  }

#pragma unroll
  for (int mi = 0; mi < 4; mi++) {
    const int row = bm + wm + mi * 16 + quad * 4;
#pragma unroll
    for (int ni = 0; ni < 4; ni++) {
      const int col = bn + wn + ni * 16 + lr;
      float* cp = C + (size_t)row * N + col;
#pragma unroll
      for (int r = 0; r < 4; r++) cp[(size_t)r * N] = acc[mi][ni][r];
    }
  }
}

// ---------------- RoPE + repack ----------------
__global__ __launch_bounds__(256) void rope_repack(
    const float* __restrict__ qkv, const float* __restrict__ cs,
    const float* __restrict__ sn, bf16_t* __restrict__ q,
    bf16_t* __restrict__ k, bf16_t* __restrict__ vt) {
  const int bs = blockIdx.x;
  const int b = bs >> 11, s = bs & 2047;
  const float* row = qkv + (size_t)bs * 3072;
  const int tid = threadIdx.x;
  for (int i = tid; i < 2048; i += 256) {
    int hh = i >> 6, d = i & 63;
    float c = cs[s * 64 + d], si = sn[s * 64 + d];
    float t = row[i];
    float other = row[(i & ~63) | ((d + 32) & 63)];
    float rot = (d < 32) ? -other : other;
    q[((size_t)(b * H_ + hh) * S_ + s) * HD_ + d] = f2bf(t * c + rot * si);
  }
  for (int i = tid; i < 512; i += 256) {
    int hh = i >> 6, d = i & 63;
    float c = cs[s * 64 + d], si = sn[s * 64 + d];
    float t = row[2048 + i];
    float other = row[2048 + ((i & ~63) | ((d + 32) & 63))];
    float rot = (d < 32) ? -other : other;
    k[((size_t)(b * KV_ + hh) * S_ + s) * HD_ + d] = f2bf(t * c + rot * si);
  }
  for (int i = tid; i < 512; i += 256) {
    int hh = i >> 6, d = i & 63;
    vt[((size_t)(b * KV_ + hh) * HD_ + d) * S_ + s] = f2bf(row[2560 + i]);
  }
}

// ---------------- flash attention (causal, GQA 4:1), LDS-staged ----------------
// Block = 64 q rows (4 waves x 16). K/V 64x64 tiles staged to LDS via
// global_load_lds (double-buffered), XOR-8 chunk swizzle for conflict-free
// ds_read_b128. All waves share one iteration count -> uniform k-loop.

// Stage a 64-row x 64-col bf16 tile (rows stride rstride elems) into lbuf.
// LDS chunk (r, sc) receives global chunk sc ^ (r&7).
__device__ __forceinline__ void stage64(const bf16_t* __restrict__ gbase, int rstride,
                                        bf16_t* lbuf, int wave, int lane) {
  const int sub = lane >> 3;      // row-within-8
  const int sc  = lane & 7;       // swizzled chunk position
  const int gc  = sc ^ sub;       // global chunk to fetch
#pragma unroll
  for (int j = 0; j < 2; j++) {
    const int r = wave * 16 + j * 8 + sub;
    load_lds16(gbase + (size_t)r * rstride + gc * 8,
               lbuf + (wave * 128 + j * 64 + lane) * 8);
  }
}

__device__ __forceinline__ void attn_qblock(
    const bf16_t* __restrict__ Q, const bf16_t* __restrict__ kb,
    const bf16_t* __restrict__ vb, bf16_t* __restrict__ O,
    bf16_t* Ks, bf16_t* Vs, bf16_t* pl,
    int bh, int q0, int wave, int lr, int quad) {
  const int b = bh >> 5, h = bh & 31;
  const int lane = quad * 16 + lr;
  const int sw = lr & 7;
  const bf16_t* qp = Q + ((size_t)bh * S_ + q0) * HD_;
  const short8 qf0 = *(const short8*)(qp + lr * HD_ + quad * 8);
  const short8 qf1 = *(const short8*)(qp + lr * HD_ + 32 + quad * 8);

  floatx4 o[4] = {};
  float m = -1e30f, l = 0.f;
  const int qg = q0 + lr;            // this lane's q column in S^T tiles
  const int nt = (q0 >> 6) + 1;      // uniform across the block's 4 waves

  stage64(kb, HD_, Ks, wave, lane);  // tile 0
  stage64(vb, S_, Vs, wave, lane);

  for (int kt = 0; kt < nt; kt++) {
    const int kk = kt * 64;
    bf16_t* Kc = Ks + (kt & 1) * 4096;
    bf16_t* Vc = Vs + (kt & 1) * 4096;
    __syncthreads();                 // staging of cur buf drained (pre-barrier vmcnt)
    if (kt + 1 < nt) {               // prefetch next tile into other buffer
      stage64(kb + (size_t)(kk + 64) * HD_, HD_, Ks + ((kt + 1) & 1) * 4096, wave, lane);
      stage64(vb + (kk + 64), S_, Vs + ((kt + 1) & 1) * 4096, wave, lane);
    }

    // S^T = K * Q^T : A-frag rows = keys, B-frag rows = queries
    floatx4 st[4] = {};
#pragma unroll
    for (int t = 0; t < 4; t++) {
      const int R = t * 16 + lr;
      const short8 kf0 = *(const short8*)&Kc[R * 64 + ((quad ^ sw) * 8)];
      const short8 kf1 = *(const short8*)&Kc[R * 64 + (((4 + quad) ^ sw) * 8)];
      st[t] = __builtin_amdgcn_mfma_f32_16x16x32_bf16(kf0, qf0, st[t], 0, 0, 0);
      st[t] = __builtin_amdgcn_mfma_f32_16x16x32_bf16(kf1, qf1, st[t], 0, 0, 0);
    }
    // mask + scale; element (t,r): k = kk + t*16 + quad*4 + r, q = qg
    float mx = -1e30f;
#pragma unroll
    for (int t = 0; t < 4; t++)
#pragma unroll
      for (int r = 0; r < 4; r++) {
        const int kg = kk + t * 16 + quad * 4 + r;
        const float v = (kg <= qg) ? st[t][r] * 0.125f : -1e30f;
        st[t][r] = v;
        mx = fmaxf(mx, v);
      }
    mx = fmaxf(mx, __shfl_xor(mx, 16, 64));
    mx = fmaxf(mx, __shfl_xor(mx, 32, 64));
    const float mn = fmaxf(m, mx);
    float rs = 0.f;
#pragma unroll
    for (int t = 0; t < 4; t++)
#pragma unroll
      for (int r = 0; r < 4; r++) {
        const float p = __expf(st[t][r] - mn);
        st[t][r] = p;
        rs += p;
      }
    rs += __shfl_xor(rs, 16, 64);
    rs += __shfl_xor(rs, 32, 64);
    const float alpha = __expf(m - mn);
    l = l * alpha + rs;
    m = mn;
#pragma unroll
    for (int r = 0; r < 4; r++) {
      const float ar = __shfl(alpha, quad * 4 + r, 16);
#pragma unroll
      for (int dt = 0; dt < 4; dt++) o[dt][r] *= ar;
    }
    // write P^T -> P rows in LDS (swizzled half-chunks, uniform 4 dwords/bank)
#pragma unroll
    for (int t = 0; t < 4; t++) {
      ushort4 pk;
      pk.x = f2bf(st[t][0]); pk.y = f2bf(st[t][1]);
      pk.z = f2bf(st[t][2]); pk.w = f2bf(st[t][3]);
      *(ushort4*)&pl[lr * 64 + (((2 * t + (quad >> 1)) ^ sw) * 8) + (quad & 1) * 4] = pk;
    }
    const short8 pf0 = *(const short8*)&pl[lr * 64 + ((quad ^ sw) * 8)];
    const short8 pf1 = *(const short8*)&pl[lr * 64 + (((4 + quad) ^ sw) * 8)];
#pragma unroll
    for (int dt = 0; dt < 4; dt++) {
      const int Rv = dt * 16 + lr;
      const short8 vf0 = *(const short8*)&Vc[Rv * 64 + ((quad ^ sw) * 8)];
      const short8 vf1 = *(const short8*)&Vc[Rv * 64 + (((4 + quad) ^ sw) * 8)];
      o[dt] = __builtin_amdgcn_mfma_f32_16x16x32_bf16(pf0, vf0, o[dt], 0, 0, 0);
      o[dt] = __builtin_amdgcn_mfma_f32_16x16x32_bf16(pf1, vf1, o[dt], 0, 0, 0);
    }
  }

  float linv[4];
#pragma unroll
  for (int r = 0; r < 4; r++) linv[r] = 1.f / __shfl(l, quad * 4 + r, 16);
  bf16_t* ob = O + ((size_t)b * S_ + q0 + quad * 4) * (H_ * HD_) + h * HD_ + lr;
#pragma unroll
  for (int dt = 0; dt < 4; dt++)
#pragma unroll
    for (int r = 0; r < 4; r++)
      ob[(size_t)r * (H_ * HD_) + dt * 16] = f2bf(o[dt][r] * linv[r]);
}

__global__ __launch_bounds__(256, 4) void flash_attn(
    const bf16_t* __restrict__ Q,   // [B*H, S, 64]
    const bf16_t* __restrict__ Kc,  // [B*KV, S, 64]
    const bf16_t* __restrict__ Vt,  // [B*KV, 64, S]
    bf16_t* __restrict__ O) {       // [B, S, H*64]
  __shared__ __attribute__((aligned(16))) bf16_t Ks[2 * 4096];  // 16 KB
  __shared__ __attribute__((aligned(16))) bf16_t Vs[2 * 4096];  // 16 KB
  __shared__ __attribute__((aligned(16))) bf16_t Pl[4][1024];   //  8 KB -> 40 KB total
  const int bh = blockIdx.y;
  const int b = bh >> 5, h = bh & 31;
  const int kvh = b * KV_ + (h >> 2);
  const int wave = threadIdx.x >> 6, lane = threadIdx.x & 63;
  const int lr = lane & 15, quad = lane >> 4;

  const bf16_t* kb = Kc + (size_t)kvh * S_ * HD_;
  const bf16_t* vb = Vt + (size_t)kvh * HD_ * S_;
  bf16_t* pl = Pl[wave];

  const int ta = blockIdx.x;        // light tile
  const int tb = 31 - blockIdx.x;   // heavy tile (combined work uniform)
  attn_qblock(Q, kb, vb, O, Ks, Vs, pl, bh, ta * 64 + wave * 16, wave, lr, quad);
  __syncthreads();                  // qblock A readers done before B's prologue stages
  attn_qblock(Q, kb, vb, O, Ks, Vs, pl, bh, tb * 64 + wave * 16, wave, lr, quad);
}

extern "C" void kernel_launch(void* const* d_in, const int* in_sizes, int n_in,
                              void* d_out, int out_size, void* d_ws, size_t ws_size,
                              hipStream_t stream) {
  const float* x    = (const float*)d_in[0];
  const float* cs   = (const float*)d_in[1];
  const float* sn   = (const float*)d_in[2];
  const float* wqkv = (const float*)d_in[3];
  const float* wout = (const float*)d_in[4];
  float* out = (float*)d_out;

  char* ws = (char*)d_ws;
  bf16_t* xb    = (bf16_t*)(ws);                 // 16,777,216 B
  bf16_t* wqkvb = (bf16_t*)(ws + 16777216);      // 12,582,912 B
  bf16_t* woutb = (bf16_t*)(ws + 29360128);      //  8,388,608 B
  float*  qkv   = (float*)(ws + 37748736);       // 50,331,648 B
  bf16_t* qb    = (bf16_t*)(ws + 88080384);      // 16,777,216 B
  bf16_t* kb    = (bf16_t*)(ws + 104857600);     //  4,194,304 B
  bf16_t* vtb   = (bf16_t*)(ws + 109051904);     //  4,194,304 B
  bf16_t* attnb = (bf16_t*)(ws + 113246208);     // 16,777,216 B

  cvt_bf16<<<8192, 256, 0, stream>>>(x, xb, 2097152);
  cvt_bf16<<<6144, 256, 0, stream>>>(wqkv, wqkvb, 1572864);
  cvt_bf16<<<4096, 256, 0, stream>>>(wout, woutb, 1048576);
  gemm_bt<<<dim3(24, 32), 256, 0, stream>>>(xb, wqkvb, qkv, 4096, 3072, 2048);
  rope_repack<<<4096, 256, 0, stream>>>(qkv, cs, sn, qb, kb, vtb);
  flash_attn<<<dim3(16, 64), 256, 0, stream>>>(qb, kb, vtb, attnb);
  gemm_bt<<<dim3(16, 32), 256, 0, stream>>>(attnb, woutb, out, 4096, 2048, 2048);
}

// Round 4
// 337.475 us; speedup vs baseline: 2.1294x; 1.1093x over previous
//
#include <hip/hip_runtime.h>

#define B_ 2
#define S_ 2048
#define D_ 2048
#define H_ 32
#define KV_ 8
#define HD_ 64

typedef unsigned short bf16_t;
typedef __attribute__((ext_vector_type(8))) short short8;
typedef __attribute__((ext_vector_type(4))) float floatx4;

__device__ __forceinline__ bf16_t f2bf(float f) {
  union { float f; unsigned u; } c; c.f = f;
  unsigned u = c.u;
  u += 0x7fffu + ((u >> 16) & 1u);          // round-to-nearest-even
  return (bf16_t)(u >> 16);
}

__device__ __forceinline__ unsigned pk_bf16(float a, float b) {
#if __has_builtin(__builtin_amdgcn_cvt_pk_bf16_f32)
  auto v = __builtin_amdgcn_cvt_pk_bf16_f32(a, b);
  unsigned u; __builtin_memcpy(&u, &v, 4); return u;
#else
  return (unsigned)f2bf(a) | ((unsigned)f2bf(b) << 16);
#endif
}

__device__ __forceinline__ float fexp2(float x) {
#if __has_builtin(__builtin_amdgcn_exp2f)
  return __builtin_amdgcn_exp2f(x);
#else
  return exp2f(x);
#endif
}

__device__ __forceinline__ void load_lds16(const void* g, void* l) {
  __builtin_amdgcn_global_load_lds(
      (const __attribute__((address_space(1))) void*)g,
      (__attribute__((address_space(3))) void*)l, 16, 0, 0);
}

// ---------------- fp32 -> bf16 convert (vectorized x4) ----------------
__global__ __launch_bounds__(256) void cvt_bf16(const float* __restrict__ in,
                                                bf16_t* __restrict__ out, int n4) {
  int i = blockIdx.x * 256 + threadIdx.x;
  if (i >= n4) return;
  float4 v = ((const float4*)in)[i];
  ushort4 o;
  o.x = f2bf(v.x); o.y = f2bf(v.y); o.z = f2bf(v.z); o.w = f2bf(v.w);
  ((ushort4*)out)[i] = o;
}

// ---------------- bf16 GEMM: C[M,N] = A[M,K] * B^T, B given [N,K] ----------------
__global__ __launch_bounds__(256) void gemm_bt(
    const bf16_t* __restrict__ A, const bf16_t* __restrict__ Bm,
    float* __restrict__ C, int M, int N, int K) {
  __shared__ __attribute__((aligned(16))) bf16_t As[128 * 32];
  __shared__ __attribute__((aligned(16))) bf16_t Bs[128 * 32];
  const int tid = threadIdx.x;
  const int lane = tid & 63;
  const int wave = tid >> 6;
  const int bm = blockIdx.y * 128, bn = blockIdx.x * 128;
  const int wm = (wave >> 1) * 64, wn = (wave & 1) * 64;
  const int lr = lane & 15, quad = lane >> 4;

  floatx4 acc[4][4] = {};

  const int t0 = tid, t1 = tid + 256;
  const int r0 = t0 >> 2, c0 = (t0 & 3) * 8;
  const int r1 = t1 >> 2, c1 = (t1 & 3) * 8;

  const bf16_t* Ab = A + (size_t)bm * K;
  const bf16_t* Bb = Bm + (size_t)bn * K;

  for (int k0 = 0; k0 < K; k0 += 32) {
    __syncthreads();
    load_lds16(Ab + (size_t)r0 * K + k0 + c0, &As[t0 * 8]);
    load_lds16(Ab + (size_t)r1 * K + k0 + c1, &As[t1 * 8]);
    load_lds16(Bb + (size_t)r0 * K + k0 + c0, &Bs[t0 * 8]);
    load_lds16(Bb + (size_t)r1 * K + k0 + c1, &Bs[t1 * 8]);
    __syncthreads();

    short8 af[4], bfr[4];
#pragma unroll
    for (int i = 0; i < 4; i++) {
      af[i]  = *(const short8*)&As[(wm + i * 16 + lr) * 32 + quad * 8];
      bfr[i] = *(const short8*)&Bs[(wn + i * 16 + lr) * 32 + quad * 8];
    }
#pragma unroll
    for (int mi = 0; mi < 4; mi++)
#pragma unroll
      for (int ni = 0; ni < 4; ni++)
        acc[mi][ni] = __builtin_amdgcn_mfma_f32_16x16x32_bf16(af[mi], bfr[ni], acc[mi][ni], 0, 0, 0);
  }

#pragma unroll
  for (int mi = 0; mi < 4; mi++) {
    const int row = bm + wm + mi * 16 + quad * 4;
#pragma unroll
    for (int ni = 0; ni < 4; ni++) {
      const int col = bn + wn + ni * 16 + lr;
      float* cp = C + (size_t)row * N + col;
#pragma unroll
      for (int r = 0; r < 4; r++) cp[(size_t)r * N] = acc[mi][ni][r];
    }
  }
}

// ---------------- fused QKV GEMM + RoPE + repack ----------------
// A = x bf16 [4096,2048], Bm = w_qkv bf16 [3072,2048].
// Epilogue: each wave's 64-col span = exactly one head. Q: rope * (0.125*log2e),
// K: rope, V: LDS-transpose then coalesced b128 rows of Vt[B,KV,64,S].
__global__ __launch_bounds__(256) void gemm_qkv(
    const bf16_t* __restrict__ A, const bf16_t* __restrict__ Bm,
    const float* __restrict__ cs, const float* __restrict__ sn,
    bf16_t* __restrict__ q, bf16_t* __restrict__ k, bf16_t* __restrict__ vt) {
  const int K = 2048;
  __shared__ __attribute__((aligned(16))) bf16_t As[128 * 32];
  __shared__ __attribute__((aligned(16))) bf16_t Bs[128 * 32];
  __shared__ __attribute__((aligned(16))) bf16_t Ts[4][64 * 72];  // V transpose scratch
  const int tid = threadIdx.x;
  const int lane = tid & 63;
  const int wave = tid >> 6;
  const int bm = blockIdx.y * 128, bn = blockIdx.x * 128;
  const int wm = (wave >> 1) * 64, wn = (wave & 1) * 64;
  const int lr = lane & 15, quad = lane >> 4;

  floatx4 acc[4][4] = {};

  const int t0 = tid, t1 = tid + 256;
  const int r0 = t0 >> 2, c0 = (t0 & 3) * 8;
  const int r1 = t1 >> 2, c1 = (t1 & 3) * 8;

  const bf16_t* Ab = A + (size_t)bm * K;
  const bf16_t* Bb = Bm + (size_t)bn * K;

  for (int k0 = 0; k0 < K; k0 += 32) {
    __syncthreads();
    load_lds16(Ab + (size_t)r0 * K + k0 + c0, &As[t0 * 8]);
    load_lds16(Ab + (size_t)r1 * K + k0 + c1, &As[t1 * 8]);
    load_lds16(Bb + (size_t)r0 * K + k0 + c0, &Bs[t0 * 8]);
    load_lds16(Bb + (size_t)r1 * K + k0 + c1, &Bs[t1 * 8]);
    __syncthreads();

    short8 af[4], bfr[4];
#pragma unroll
    for (int i = 0; i < 4; i++) {
      af[i]  = *(const short8*)&As[(wm + i * 16 + lr) * 32 + quad * 8];
      bfr[i] = *(const short8*)&Bs[(wn + i * 16 + lr) * 32 + quad * 8];
    }
#pragma unroll
    for (int mi = 0; mi < 4; mi++)
#pragma unroll
      for (int ni = 0; ni < 4; ni++)
        acc[mi][ni] = __builtin_amdgcn_mfma_f32_16x16x32_bf16(af[mi], bfr[ni], acc[mi][ni], 0, 0, 0);
  }

  const int f0 = bn + wn;              // wave-uniform feature base (multiple of 64)
  const int srow0 = bm + wm;
  const int bb = srow0 >> 11, s0 = srow0 & 2047;

  if (f0 < 2560) {                     // Q or K head: in-register rope
    const bool isq = (f0 < 2048);
    const float scale = isq ? 0.18033688011f : 1.0f;   // 0.125 * log2(e)
    bf16_t* dst = isq ? (q + (size_t)(bb * H_ + (f0 >> 6)) * S_ * HD_)
                      : (k + (size_t)(bb * KV_ + ((f0 - 2048) >> 6)) * S_ * HD_);
#pragma unroll
    for (int mi = 0; mi < 4; mi++) {
#pragma unroll
      for (int r = 0; r < 4; r++) {
        const int sr = s0 + mi * 16 + quad * 4 + r;
        const float* cp = cs + sr * HD_;
        const float* sp = sn + sr * HD_;
        bf16_t* drow = dst + (size_t)sr * HD_;
#pragma unroll
        for (int ni = 0; ni < 4; ni++) {
          const int d = ni * 16 + lr;
          const float t = acc[mi][ni][r];
          const float oth = acc[mi][ni ^ 2][r];
          const float rot = (ni < 2) ? -oth : oth;   // d<32 iff ni<2
          drow[d] = f2bf((t * cp[d] + rot * sp[d]) * scale);
        }
      }
    }
  } else {                             // V head: transpose via own LDS region
    const int hv = (f0 - 2560) >> 6;
    bf16_t* ts = Ts[wave];
#pragma unroll
    for (int ni = 0; ni < 4; ni++)
#pragma unroll
      for (int mi = 0; mi < 4; mi++) {
        uint2 pw;
        pw.x = pk_bf16(acc[mi][ni][0], acc[mi][ni][1]);
        pw.y = pk_bf16(acc[mi][ni][2], acc[mi][ni][3]);
        *(uint2*)&ts[(ni * 16 + lr) * 72 + mi * 16 + quad * 4] = pw;
      }
    // same-wave RAW -> compiler-inserted lgkmcnt wait; no barrier needed
    bf16_t* vrow = vt + ((size_t)(bb * KV_ + hv) * HD_ + lane) * S_ + s0;
#pragma unroll
    for (int j = 0; j < 8; j++)
      *(short8*)(vrow + j * 8) = *(const short8*)&ts[lane * 72 + j * 8];
  }
}

// ---------------- flash attention (causal, GQA 4:1), LDS-staged ----------------
// Q pre-scaled by 0.125*log2e -> softmax in exp2 domain. Mask only on the
// diagonal tile. K/V 64x64 tiles double-buffered via global_load_lds.
__device__ __forceinline__ void stage64(const bf16_t* __restrict__ gbase, int rstride,
                                        bf16_t* lbuf, int wave, int lane) {
  const int sub = lane >> 3;
  const int sc  = lane & 7;
  const int gc  = sc ^ sub;
#pragma unroll
  for (int j = 0; j < 2; j++) {
    const int r = wave * 16 + j * 8 + sub;
    load_lds16(gbase + (size_t)r * rstride + gc * 8,
               lbuf + (wave * 128 + j * 64 + lane) * 8);
  }
}

__device__ __forceinline__ void attn_qblock(
    const bf16_t* __restrict__ Q, const bf16_t* __restrict__ kb,
    const bf16_t* __restrict__ vb, bf16_t* __restrict__ O,
    bf16_t* Ks, bf16_t* Vs, bf16_t* pl,
    int bh, int q0, int wave, int lr, int quad) {
  const int b = bh >> 5, h = bh & 31;
  const int lane = quad * 16 + lr;
  const int sw = lr & 7;
  const bf16_t* qp = Q + ((size_t)bh * S_ + q0) * HD_;
  const short8 qf0 = *(const short8*)(qp + lr * HD_ + quad * 8);
  const short8 qf1 = *(const short8*)(qp + lr * HD_ + 32 + quad * 8);

  floatx4 o[4] = {};
  float m = -1e30f, l = 0.f;
  const int qg = q0 + lr;
  const int nt = (q0 >> 6) + 1;      // uniform across the block's 4 waves

  stage64(kb, HD_, Ks, wave, lane);
  stage64(vb, S_, Vs, wave, lane);

  for (int kt = 0; kt < nt; kt++) {
    const int kk = kt * 64;
    bf16_t* Kc = Ks + (kt & 1) * 4096;
    bf16_t* Vc = Vs + (kt & 1) * 4096;
    __syncthreads();
    if (kt + 1 < nt) {
      stage64(kb + (size_t)(kk + 64) * HD_, HD_, Ks + ((kt + 1) & 1) * 4096, wave, lane);
      stage64(vb + (kk + 64), S_, Vs + ((kt + 1) & 1) * 4096, wave, lane);
    }

    floatx4 st[4] = {};
#pragma unroll
    for (int t = 0; t < 4; t++) {
      const int R = t * 16 + lr;
      const short8 kf0 = *(const short8*)&Kc[R * 64 + ((quad ^ sw) * 8)];
      const short8 kf1 = *(const short8*)&Kc[R * 64 + (((4 + quad) ^ sw) * 8)];
      st[t] = __builtin_amdgcn_mfma_f32_16x16x32_bf16(kf0, qf0, st[t], 0, 0, 0);
      st[t] = __builtin_amdgcn_mfma_f32_16x16x32_bf16(kf1, qf1, st[t], 0, 0, 0);
    }
    float mx = -1e30f;
    if (kt == nt - 1) {              // diagonal tile: apply causal mask
#pragma unroll
      for (int t = 0; t < 4; t++)
#pragma unroll
        for (int r = 0; r < 4; r++) {
          const int kg = kk + t * 16 + quad * 4 + r;
          const float v = (kg <= qg) ? st[t][r] : -1e30f;
          st[t][r] = v;
          mx = fmaxf(mx, v);
        }
    } else {                          // full tile: no mask
#pragma unroll
      for (int t = 0; t < 4; t++)
#pragma unroll
        for (int r = 0; r < 4; r++) mx = fmaxf(mx, st[t][r]);
    }
    mx = fmaxf(mx, __shfl_xor(mx, 16, 64));
    mx = fmaxf(mx, __shfl_xor(mx, 32, 64));
    const float mn = fmaxf(m, mx);
    float rs = 0.f;
#pragma unroll
    for (int t = 0; t < 4; t++)
#pragma unroll
      for (int r = 0; r < 4; r++) {
        const float p = fexp2(st[t][r] - mn);
        st[t][r] = p;
        rs += p;
      }
    rs += __shfl_xor(rs, 16, 64);
    rs += __shfl_xor(rs, 32, 64);
    const float alpha = fexp2(m - mn);
    l = l * alpha + rs;
    m = mn;
#pragma unroll
    for (int r = 0; r < 4; r++) {
      const float ar = __shfl(alpha, quad * 4 + r, 16);
#pragma unroll
      for (int dt = 0; dt < 4; dt++) o[dt][r] *= ar;
    }
#pragma unroll
    for (int t = 0; t < 4; t++) {
      uint2 pw;
      pw.x = pk_bf16(st[t][0], st[t][1]);
      pw.y = pk_bf16(st[t][2], st[t][3]);
      *(uint2*)&pl[lr * 64 + (((2 * t + (quad >> 1)) ^ sw) * 8) + (quad & 1) * 4] = pw;
    }
    const short8 pf0 = *(const short8*)&pl[lr * 64 + ((quad ^ sw) * 8)];
    const short8 pf1 = *(const short8*)&pl[lr * 64 + (((4 + quad) ^ sw) * 8)];
#pragma unroll
    for (int dt = 0; dt < 4; dt++) {
      const int Rv = dt * 16 + lr;
      const short8 vf0 = *(const short8*)&Vc[Rv * 64 + ((quad ^ sw) * 8)];
      const short8 vf1 = *(const short8*)&Vc[Rv * 64 + (((4 + quad) ^ sw) * 8)];
      o[dt] = __builtin_amdgcn_mfma_f32_16x16x32_bf16(pf0, vf0, o[dt], 0, 0, 0);
      o[dt] = __builtin_amdgcn_mfma_f32_16x16x32_bf16(pf1, vf1, o[dt], 0, 0, 0);
    }
  }

  float linv[4];
#pragma unroll
  for (int r = 0; r < 4; r++) linv[r] = 1.f / __shfl(l, quad * 4 + r, 16);
  bf16_t* ob = O + ((size_t)b * S_ + q0 + quad * 4) * (H_ * HD_) + h * HD_ + lr;
#pragma unroll
  for (int dt = 0; dt < 4; dt++)
#pragma unroll
    for (int r = 0; r < 4; r++)
      ob[(size_t)r * (H_ * HD_) + dt * 16] = f2bf(o[dt][r] * linv[r]);
}

__global__ __launch_bounds__(256, 4) void flash_attn(
    const bf16_t* __restrict__ Q,   // [B*H, S, 64] (pre-scaled)
    const bf16_t* __restrict__ Kc,  // [B*KV, S, 64]
    const bf16_t* __restrict__ Vt,  // [B*KV, 64, S]
    bf16_t* __restrict__ O) {       // [B, S, H*64]
  __shared__ __attribute__((aligned(16))) bf16_t Ks[2 * 4096];
  __shared__ __attribute__((aligned(16))) bf16_t Vs[2 * 4096];
  __shared__ __attribute__((aligned(16))) bf16_t Pl[4][1024];
  const int bh = blockIdx.y;
  const int b = bh >> 5, h = bh & 31;
  const int kvh = b * KV_ + (h >> 2);
  const int wave = threadIdx.x >> 6, lane = threadIdx.x & 63;
  const int lr = lane & 15, quad = lane >> 4;

  const bf16_t* kb = Kc + (size_t)kvh * S_ * HD_;
  const bf16_t* vb = Vt + (size_t)kvh * HD_ * S_;
  bf16_t* pl = Pl[wave];

  const int ta = blockIdx.x;
  const int tb = 31 - blockIdx.x;
  attn_qblock(Q, kb, vb, O, Ks, Vs, pl, bh, ta * 64 + wave * 16, wave, lr, quad);
  __syncthreads();
  attn_qblock(Q, kb, vb, O, Ks, Vs, pl, bh, tb * 64 + wave * 16, wave, lr, quad);
}

extern "C" void kernel_launch(void* const* d_in, const int* in_sizes, int n_in,
                              void* d_out, int out_size, void* d_ws, size_t ws_size,
                              hipStream_t stream) {
  const float* x    = (const float*)d_in[0];
  const float* cs   = (const float*)d_in[1];
  const float* sn   = (const float*)d_in[2];
  const float* wqkv = (const float*)d_in[3];
  const float* wout = (const float*)d_in[4];
  float* out = (float*)d_out;

  char* ws = (char*)d_ws;
  bf16_t* xb    = (bf16_t*)(ws);                 // 16,777,216 B
  bf16_t* wqkvb = (bf16_t*)(ws + 16777216);      // 12,582,912 B
  bf16_t* woutb = (bf16_t*)(ws + 29360128);      //  8,388,608 B
  bf16_t* qb    = (bf16_t*)(ws + 37748736);      // 16,777,216 B
  bf16_t* kb    = (bf16_t*)(ws + 54525952);      //  4,194,304 B
  bf16_t* vtb   = (bf16_t*)(ws + 58720256);      //  4,194,304 B
  bf16_t* attnb = (bf16_t*)(ws + 62914560);      // 16,777,216 B  (total ~76 MB)

  cvt_bf16<<<8192, 256, 0, stream>>>(x, xb, 2097152);
  cvt_bf16<<<6144, 256, 0, stream>>>(wqkv, wqkvb, 1572864);
  cvt_bf16<<<4096, 256, 0, stream>>>(wout, woutb, 1048576);
  gemm_qkv<<<dim3(24, 32), 256, 0, stream>>>(xb, wqkvb, cs, sn, qb, kb, vtb);
  flash_attn<<<dim3(16, 64), 256, 0, stream>>>(qb, kb, vtb, attnb);
  gemm_bt<<<dim3(16, 32), 256, 0, stream>>>(attnb, woutb, out, 4096, 2048, 2048);
}

// Round 5
// 331.893 us; speedup vs baseline: 2.1652x; 1.0168x over previous
//
#include <hip/hip_runtime.h>
#include <hip/hip_fp16.h>

#define B_ 2
#define S_ 2048
#define D_ 2048
#define H_ 32
#define KV_ 8
#define HD_ 64

typedef unsigned short bf16_t;
typedef __attribute__((ext_vector_type(8))) short short8;
typedef __attribute__((ext_vector_type(4))) float floatx4;
typedef __attribute__((ext_vector_type(2))) float float2v;

__device__ __forceinline__ bf16_t f2bf(float f) {
  union { float f; unsigned u; } c; c.f = f;
  unsigned u = c.u;
  u += 0x7fffu + ((u >> 16) & 1u);          // round-to-nearest-even
  return (bf16_t)(u >> 16);
}

__device__ __forceinline__ unsigned pk_bf16(float a, float b) {
#if __has_builtin(__builtin_amdgcn_cvt_pk_bf16_f32)
  auto v = __builtin_amdgcn_cvt_pk_bf16_f32(a, b);
  unsigned u; __builtin_memcpy(&u, &v, 4); return u;
#else
  return (unsigned)f2bf(a) | ((unsigned)f2bf(b) << 16);
#endif
}

__device__ __forceinline__ float fexp2(float x) {
#if __has_builtin(__builtin_amdgcn_exp2f)
  return __builtin_amdgcn_exp2f(x);
#else
  return exp2f(x);
#endif
}

__device__ __forceinline__ void load_lds16(const void* g, void* l) {
  __builtin_amdgcn_global_load_lds(
      (const __attribute__((address_space(1))) void*)g,
      (__attribute__((address_space(3))) void*)l, 16, 0, 0);
}

// ---------------- prep: fp32->bf16 casts + packed fp16 rope table ----------------
__device__ __forceinline__ void cvt4(const float* __restrict__ in,
                                     bf16_t* __restrict__ out, int i) {
  float4 v = ((const float4*)in)[i];
  ushort4 o;
  o.x = f2bf(v.x); o.y = f2bf(v.y); o.z = f2bf(v.z); o.w = f2bf(v.w);
  ((ushort4*)out)[i] = o;
}

__global__ __launch_bounds__(256) void prep(
    const float* __restrict__ x, bf16_t* __restrict__ xb,
    const float* __restrict__ wqkv, bf16_t* __restrict__ wqkvb,
    const float* __restrict__ wout, bf16_t* __restrict__ woutb,
    const float* __restrict__ cs, const float* __restrict__ sn,
    unsigned* __restrict__ tab) {
  const int bid = blockIdx.x;
  if (bid < 8192) {
    cvt4(x, xb, bid * 256 + threadIdx.x);
  } else if (bid < 14336) {
    cvt4(wqkv, wqkvb, (bid - 8192) * 256 + threadIdx.x);
  } else if (bid < 18432) {
    cvt4(wout, woutb, (bid - 14336) * 256 + threadIdx.x);
  } else {
    const int i = (bid - 18432) * 256 + threadIdx.x;   // 131072 entries
    __half2 h = __floats2half2_rn(cs[i], sn[i]);
    unsigned u; __builtin_memcpy(&u, &h, 4);
    tab[i] = u;
  }
}

// ---------------- bf16 GEMM: C[M,N] = A[M,K] * B^T (f32 out) ----------------
__global__ __launch_bounds__(256) void gemm_bt(
    const bf16_t* __restrict__ A, const bf16_t* __restrict__ Bm,
    float* __restrict__ C, int M, int N, int K) {
  __shared__ __attribute__((aligned(16))) bf16_t As[128 * 32];
  __shared__ __attribute__((aligned(16))) bf16_t Bs[128 * 32];
  const int tid = threadIdx.x;
  const int lane = tid & 63;
  const int wave = tid >> 6;
  const int bm = blockIdx.y * 128, bn = blockIdx.x * 128;
  const int wm = (wave >> 1) * 64, wn = (wave & 1) * 64;
  const int lr = lane & 15, quad = lane >> 4;

  floatx4 acc[4][4] = {};

  const int t0 = tid, t1 = tid + 256;
  const int r0 = t0 >> 2, c0 = (t0 & 3) * 8;
  const int r1 = t1 >> 2, c1 = (t1 & 3) * 8;

  const bf16_t* Ab = A + (size_t)bm * K;
  const bf16_t* Bb = Bm + (size_t)bn * K;

  for (int k0 = 0; k0 < K; k0 += 32) {
    __syncthreads();
    load_lds16(Ab + (size_t)r0 * K + k0 + c0, &As[t0 * 8]);
    load_lds16(Ab + (size_t)r1 * K + k0 + c1, &As[t1 * 8]);
    load_lds16(Bb + (size_t)r0 * K + k0 + c0, &Bs[t0 * 8]);
    load_lds16(Bb + (size_t)r1 * K + k0 + c1, &Bs[t1 * 8]);
    __syncthreads();

    short8 af[4], bfr[4];
#pragma unroll
    for (int i = 0; i < 4; i++) {
      af[i]  = *(const short8*)&As[(wm + i * 16 + lr) * 32 + quad * 8];
      bfr[i] = *(const short8*)&Bs[(wn + i * 16 + lr) * 32 + quad * 8];
    }
#pragma unroll
    for (int mi = 0; mi < 4; mi++)
#pragma unroll
      for (int ni = 0; ni < 4; ni++)
        acc[mi][ni] = __builtin_amdgcn_mfma_f32_16x16x32_bf16(af[mi], bfr[ni], acc[mi][ni], 0, 0, 0);
  }

#pragma unroll
  for (int mi = 0; mi < 4; mi++) {
    const int row = bm + wm + mi * 16 + quad * 4;
#pragma unroll
    for (int ni = 0; ni < 4; ni++) {
      const int col = bn + wn + ni * 16 + lr;
      float* cp = C + (size_t)row * N + col;
#pragma unroll
      for (int r = 0; r < 4; r++) cp[(size_t)r * N] = acc[mi][ni][r];
    }
  }
}

// ---------------- fused QKV GEMM + RoPE (fp16 table) + repack ----------------
__global__ __launch_bounds__(256) void gemm_qkv(
    const bf16_t* __restrict__ A, const bf16_t* __restrict__ Bm,
    const unsigned* __restrict__ tab,
    bf16_t* __restrict__ q, bf16_t* __restrict__ k, bf16_t* __restrict__ vt) {
  const int K = 2048;
  __shared__ __attribute__((aligned(16))) bf16_t As[128 * 32];
  __shared__ __attribute__((aligned(16))) bf16_t Bs[128 * 32];
  __shared__ __attribute__((aligned(16))) bf16_t Ts[4][64 * 72];  // V transpose scratch
  const int tid = threadIdx.x;
  const int lane = tid & 63;
  const int wave = tid >> 6;
  const int bm = blockIdx.y * 128, bn = blockIdx.x * 128;
  const int wm = (wave >> 1) * 64, wn = (wave & 1) * 64;
  const int lr = lane & 15, quad = lane >> 4;

  floatx4 acc[4][4] = {};

  const int t0 = tid, t1 = tid + 256;
  const int r0 = t0 >> 2, c0 = (t0 & 3) * 8;
  const int r1 = t1 >> 2, c1 = (t1 & 3) * 8;

  const bf16_t* Ab = A + (size_t)bm * K;
  const bf16_t* Bb = Bm + (size_t)bn * K;

  for (int k0 = 0; k0 < K; k0 += 32) {
    __syncthreads();
    load_lds16(Ab + (size_t)r0 * K + k0 + c0, &As[t0 * 8]);
    load_lds16(Ab + (size_t)r1 * K + k0 + c1, &As[t1 * 8]);
    load_lds16(Bb + (size_t)r0 * K + k0 + c0, &Bs[t0 * 8]);
    load_lds16(Bb + (size_t)r1 * K + k0 + c1, &Bs[t1 * 8]);
    __syncthreads();

    short8 af[4], bfr[4];
#pragma unroll
    for (int i = 0; i < 4; i++) {
      af[i]  = *(const short8*)&As[(wm + i * 16 + lr) * 32 + quad * 8];
      bfr[i] = *(const short8*)&Bs[(wn + i * 16 + lr) * 32 + quad * 8];
    }
#pragma unroll
    for (int mi = 0; mi < 4; mi++)
#pragma unroll
      for (int ni = 0; ni < 4; ni++)
        acc[mi][ni] = __builtin_amdgcn_mfma_f32_16x16x32_bf16(af[mi], bfr[ni], acc[mi][ni], 0, 0, 0);
  }

  const int f0 = bn + wn;              // wave-uniform feature base (multiple of 64)
  const int srow0 = bm + wm;
  const int bb = srow0 >> 11, s0 = srow0 & 2047;

  if (f0 < 2560) {                     // Q or K head: in-register rope
    const bool isq = (f0 < 2048);
    const float scale = isq ? 0.18033688011f : 1.0f;   // 0.125 * log2(e)
    bf16_t* dst = isq ? (q + (size_t)(bb * H_ + (f0 >> 6)) * S_ * HD_)
                      : (k + (size_t)(bb * KV_ + ((f0 - 2048) >> 6)) * S_ * HD_);
#pragma unroll
    for (int mi = 0; mi < 4; mi++) {
#pragma unroll
      for (int r = 0; r < 4; r++) {
        const int sr = s0 + mi * 16 + quad * 4 + r;
        const unsigned* tp = tab + (size_t)sr * HD_;
        bf16_t* drow = dst + (size_t)sr * HD_;
#pragma unroll
        for (int ni = 0; ni < 4; ni++) {
          const int d = ni * 16 + lr;
          const unsigned w = tp[d];
          __half2 h2; __builtin_memcpy(&h2, &w, 4);
          const float2 cf = __half22float2(h2);
          const float t = acc[mi][ni][r];
          const float oth = acc[mi][ni ^ 2][r];
          const float rot = (ni < 2) ? -oth : oth;   // d<32 iff ni<2
          drow[d] = f2bf((t * cf.x + rot * cf.y) * scale);
        }
      }
    }
  } else {                             // V head: transpose via own LDS region
    const int hv = (f0 - 2560) >> 6;
    bf16_t* ts = Ts[wave];
#pragma unroll
    for (int ni = 0; ni < 4; ni++)
#pragma unroll
      for (int mi = 0; mi < 4; mi++) {
        uint2 pw;
        pw.x = pk_bf16(acc[mi][ni][0], acc[mi][ni][1]);
        pw.y = pk_bf16(acc[mi][ni][2], acc[mi][ni][3]);
        *(uint2*)&ts[(ni * 16 + lr) * 72 + mi * 16 + quad * 4] = pw;
      }
    bf16_t* vrow = vt + ((size_t)(bb * KV_ + hv) * HD_ + lane) * S_ + s0;
#pragma unroll
    for (int j = 0; j < 8; j++)
      *(short8*)(vrow + j * 8) = *(const short8*)&ts[lane * 72 + j * 8];
  }
}

// ---------------- flash attention (causal, GQA 4:1), O^T formulation ----------------
// st = mfma(K,Q) -> S^T (q on lanes); o = mfma(V,P) -> O^T (q on lanes) so
// alpha/l are lane-local. Rescale skipped when no lane saw a new max.
__device__ __forceinline__ void stage64(const bf16_t* __restrict__ gbase, int rstride,
                                        bf16_t* lbuf, int wave, int lane) {
  const int sub = lane >> 3;
  const int sc  = lane & 7;
  const int gc  = sc ^ sub;
#pragma unroll
  for (int j = 0; j < 2; j++) {
    const int r = wave * 16 + j * 8 + sub;
    load_lds16(gbase + (size_t)r * rstride + gc * 8,
               lbuf + (wave * 128 + j * 64 + lane) * 8);
  }
}

__device__ __forceinline__ void attn_qblock(
    const bf16_t* __restrict__ Q, const bf16_t* __restrict__ kb,
    const bf16_t* __restrict__ vb, bf16_t* __restrict__ O,
    bf16_t* Ks, bf16_t* Vs, bf16_t* pl,
    int bh, int q0, int wave, int lr, int quad) {
  const int b = bh >> 5, h = bh & 31;
  const int lane = quad * 16 + lr;
  const int sw = lr & 7;
  const bf16_t* qp = Q + ((size_t)bh * S_ + q0) * HD_;
  const short8 qf0 = *(const short8*)(qp + lr * HD_ + quad * 8);
  const short8 qf1 = *(const short8*)(qp + lr * HD_ + 32 + quad * 8);

  floatx4 o[4] = {};                 // O^T: reg r -> d = dt*16+quad*4+r, lane -> q=lr
  float m = -1e30f, l = 0.f;
  const int qg = q0 + lr;
  const int nt = (q0 >> 6) + 1;      // uniform across the block's 4 waves

  stage64(kb, HD_, Ks, wave, lane);
  stage64(vb, S_, Vs, wave, lane);

  for (int kt = 0; kt < nt; kt++) {
    const int kk = kt * 64;
    bf16_t* Kc = Ks + (kt & 1) * 4096;
    bf16_t* Vc = Vs + (kt & 1) * 4096;
    __syncthreads();
    if (kt + 1 < nt) {
      stage64(kb + (size_t)(kk + 64) * HD_, HD_, Ks + ((kt + 1) & 1) * 4096, wave, lane);
      stage64(vb + (kk + 64), S_, Vs + ((kt + 1) & 1) * 4096, wave, lane);
    }

    floatx4 st[4] = {};
#pragma unroll
    for (int t = 0; t < 4; t++) {
      const int R = t * 16 + lr;
      const short8 kf0 = *(const short8*)&Kc[R * 64 + ((quad ^ sw) * 8)];
      const short8 kf1 = *(const short8*)&Kc[R * 64 + (((4 + quad) ^ sw) * 8)];
      st[t] = __builtin_amdgcn_mfma_f32_16x16x32_bf16(kf0, qf0, st[t], 0, 0, 0);
      st[t] = __builtin_amdgcn_mfma_f32_16x16x32_bf16(kf1, qf1, st[t], 0, 0, 0);
    }
    if (kt == nt - 1) {              // diagonal tile: causal mask
#pragma unroll
      for (int t = 0; t < 4; t++)
#pragma unroll
        for (int r = 0; r < 4; r++) {
          const int kg = kk + t * 16 + quad * 4 + r;
          st[t][r] = (kg <= qg) ? st[t][r] : -1e30f;
        }
    }
    float2v mx2 = { -3e30f, -3e30f };
#pragma unroll
    for (int t = 0; t < 4; t++) {
      const float2v lo = { st[t][0], st[t][1] };
      const float2v hi = { st[t][2], st[t][3] };
      mx2 = __builtin_elementwise_max(mx2, __builtin_elementwise_max(lo, hi));
    }
    float mx = fmaxf(mx2.x, mx2.y);
    mx = fmaxf(mx, __shfl_xor(mx, 16, 64));
    mx = fmaxf(mx, __shfl_xor(mx, 32, 64));
    const float mn = fmaxf(m, mx);
    const float2v mn2 = { mn, mn };
    float2v rs2 = { 0.f, 0.f };
#pragma unroll
    for (int t = 0; t < 4; t++) {
      float2v lo = { st[t][0], st[t][1] };
      float2v hi = { st[t][2], st[t][3] };
      lo = lo - mn2; hi = hi - mn2;
      const float p0 = fexp2(lo.x), p1 = fexp2(lo.y);
      const float p2 = fexp2(hi.x), p3 = fexp2(hi.y);
      st[t][0] = p0; st[t][1] = p1; st[t][2] = p2; st[t][3] = p3;
      const float2v pa = { p0, p1 }, pb = { p2, p3 };
      rs2 = rs2 + pa + pb;
    }
    float rs = rs2.x + rs2.y;
    rs += __shfl_xor(rs, 16, 64);
    rs += __shfl_xor(rs, 32, 64);
    if (__all(mn == m)) {
      l += rs;
    } else {
      const float a = fexp2(m - mn);
      l = l * a + rs;
      m = mn;
      const floatx4 a4 = { a, a, a, a };
#pragma unroll
      for (int dt = 0; dt < 4; dt++) o[dt] *= a4;
    }
#pragma unroll
    for (int t = 0; t < 4; t++) {
      uint2 pw;
      pw.x = pk_bf16(st[t][0], st[t][1]);
      pw.y = pk_bf16(st[t][2], st[t][3]);
      *(uint2*)&pl[lr * 64 + (((2 * t + (quad >> 1)) ^ sw) * 8) + (quad & 1) * 4] = pw;
    }
    const short8 pf0 = *(const short8*)&pl[lr * 64 + ((quad ^ sw) * 8)];
    const short8 pf1 = *(const short8*)&pl[lr * 64 + (((4 + quad) ^ sw) * 8)];
#pragma unroll
    for (int dt = 0; dt < 4; dt++) {
      const int Rv = dt * 16 + lr;
      const short8 vf0 = *(const short8*)&Vc[Rv * 64 + ((quad ^ sw) * 8)];
      const short8 vf1 = *(const short8*)&Vc[Rv * 64 + (((4 + quad) ^ sw) * 8)];
      o[dt] = __builtin_amdgcn_mfma_f32_16x16x32_bf16(vf0, pf0, o[dt], 0, 0, 0);
      o[dt] = __builtin_amdgcn_mfma_f32_16x16x32_bf16(vf1, pf1, o[dt], 0, 0, 0);
    }
  }

  const float linv = 1.f / l;        // lane-local (q = lr)
  const floatx4 lv = { linv, linv, linv, linv };
  bf16_t* ob = O + ((size_t)b * S_ + q0 + lr) * (H_ * HD_) + h * HD_ + quad * 4;
#pragma unroll
  for (int dt = 0; dt < 4; dt++) {
    const floatx4 ov = o[dt] * lv;
    uint2 pw;
    pw.x = pk_bf16(ov[0], ov[1]);
    pw.y = pk_bf16(ov[2], ov[3]);
    *(uint2*)(ob + dt * 16) = pw;
  }
}

__global__ __launch_bounds__(256, 4) void flash_attn(
    const bf16_t* __restrict__ Q,   // [B*H, S, 64] (pre-scaled by 0.125*log2e)
    const bf16_t* __restrict__ Kc,  // [B*KV, S, 64]
    const bf16_t* __restrict__ Vt,  // [B*KV, 64, S]
    bf16_t* __restrict__ O) {       // [B, S, H*64]
  __shared__ __attribute__((aligned(16))) bf16_t Ks[2 * 4096];
  __shared__ __attribute__((aligned(16))) bf16_t Vs[2 * 4096];
  __shared__ __attribute__((aligned(16))) bf16_t Pl[4][1024];
  const int bh = blockIdx.y;
  const int b = bh >> 5, h = bh & 31;
  const int kvh = b * KV_ + (h >> 2);
  const int wave = threadIdx.x >> 6, lane = threadIdx.x & 63;
  const int lr = lane & 15, quad = lane >> 4;

  const bf16_t* kb = Kc + (size_t)kvh * S_ * HD_;
  const bf16_t* vb = Vt + (size_t)kvh * HD_ * S_;
  bf16_t* pl = Pl[wave];

  const int ta = blockIdx.x;
  const int tb = 31 - blockIdx.x;
  attn_qblock(Q, kb, vb, O, Ks, Vs, pl, bh, ta * 64 + wave * 16, wave, lr, quad);
  __syncthreads();
  attn_qblock(Q, kb, vb, O, Ks, Vs, pl, bh, tb * 64 + wave * 16, wave, lr, quad);
}

extern "C" void kernel_launch(void* const* d_in, const int* in_sizes, int n_in,
                              void* d_out, int out_size, void* d_ws, size_t ws_size,
                              hipStream_t stream) {
  const float* x    = (const float*)d_in[0];
  const float* cs   = (const float*)d_in[1];
  const float* sn   = (const float*)d_in[2];
  const float* wqkv = (const float*)d_in[3];
  const float* wout = (const float*)d_in[4];
  float* out = (float*)d_out;

  char* ws = (char*)d_ws;
  bf16_t*  xb    = (bf16_t*)(ws);                 // 16,777,216 B
  bf16_t*  wqkvb = (bf16_t*)(ws + 16777216);      // 12,582,912 B
  bf16_t*  woutb = (bf16_t*)(ws + 29360128);      //  8,388,608 B
  bf16_t*  qb    = (bf16_t*)(ws + 37748736);      // 16,777,216 B
  bf16_t*  kb    = (bf16_t*)(ws + 54525952);      //  4,194,304 B
  bf16_t*  vtb   = (bf16_t*)(ws + 58720256);      //  4,194,304 B
  bf16_t*  attnb = (bf16_t*)(ws + 62914560);      // 16,777,216 B
  unsigned* tab  = (unsigned*)(ws + 79691776);    //    524,288 B (total ~80 MB)

  prep<<<18944, 256, 0, stream>>>(x, xb, wqkv, wqkvb, wout, woutb, cs, sn, tab);
  gemm_qkv<<<dim3(24, 32), 256, 0, stream>>>(xb, wqkvb, tab, qb, kb, vtb);
  flash_attn<<<dim3(16, 64), 256, 0, stream>>>(qb, kb, vtb, attnb);
  gemm_bt<<<dim3(16, 32), 256, 0, stream>>>(attnb, woutb, out, 4096, 2048, 2048);
}

// Round 6
// 309.450 us; speedup vs baseline: 2.3222x; 1.0725x over previous
//
#include <hip/hip_runtime.h>
#include <hip/hip_fp16.h>

#define B_ 2
#define S_ 2048
#define D_ 2048
#define H_ 32
#define KV_ 8
#define HD_ 64

typedef unsigned short bf16_t;
typedef __attribute__((ext_vector_type(8))) short short8;
typedef __attribute__((ext_vector_type(4))) float floatx4;
typedef __attribute__((ext_vector_type(2))) float float2v;

__device__ __forceinline__ bf16_t f2bf(float f) {
  union { float f; unsigned u; } c; c.f = f;
  unsigned u = c.u;
  u += 0x7fffu + ((u >> 16) & 1u);          // round-to-nearest-even
  return (bf16_t)(u >> 16);
}

__device__ __forceinline__ unsigned pk_bf16(float a, float b) {
#if __has_builtin(__builtin_amdgcn_cvt_pk_bf16_f32)
  auto v = __builtin_amdgcn_cvt_pk_bf16_f32(a, b);
  unsigned u; __builtin_memcpy(&u, &v, 4); return u;
#else
  return (unsigned)f2bf(a) | ((unsigned)f2bf(b) << 16);
#endif
}

__device__ __forceinline__ float fexp2(float x) {
#if __has_builtin(__builtin_amdgcn_exp2f)
  return __builtin_amdgcn_exp2f(x);
#else
  return exp2f(x);
#endif
}

__device__ __forceinline__ void load_lds16(const void* g, void* l) {
  __builtin_amdgcn_global_load_lds(
      (const __attribute__((address_space(1))) void*)g,
      (__attribute__((address_space(3))) void*)l, 16, 0, 0);
}

// ---------------- prep: fp32->bf16 casts + packed fp16 rope table ----------------
__device__ __forceinline__ void cvt4(const float* __restrict__ in,
                                     bf16_t* __restrict__ out, int i) {
  float4 v = ((const float4*)in)[i];
  ushort4 o;
  o.x = f2bf(v.x); o.y = f2bf(v.y); o.z = f2bf(v.z); o.w = f2bf(v.w);
  ((ushort4*)out)[i] = o;
}

__global__ __launch_bounds__(256) void prep(
    const float* __restrict__ x, bf16_t* __restrict__ xb,
    const float* __restrict__ wqkv, bf16_t* __restrict__ wqkvb,
    const float* __restrict__ wout, bf16_t* __restrict__ woutb,
    const float* __restrict__ cs, const float* __restrict__ sn,
    unsigned* __restrict__ tab) {
  const int bid = blockIdx.x;
  if (bid < 8192) {
    cvt4(x, xb, bid * 256 + threadIdx.x);
  } else if (bid < 14336) {
    cvt4(wqkv, wqkvb, (bid - 8192) * 256 + threadIdx.x);
  } else if (bid < 18432) {
    cvt4(wout, woutb, (bid - 14336) * 256 + threadIdx.x);
  } else {
    const int i = (bid - 18432) * 256 + threadIdx.x;   // 131072 entries
    __half2 h = __floats2half2_rn(cs[i], sn[i]);
    unsigned u; __builtin_memcpy(&u, &h, 4);
    tab[i] = u;
  }
}

// ---------------- bf16 GEMM: C[M,N] = A[M,K] * B^T (f32 out) ----------------
__global__ __launch_bounds__(256) void gemm_bt(
    const bf16_t* __restrict__ A, const bf16_t* __restrict__ Bm,
    float* __restrict__ C, int M, int N, int K) {
  __shared__ __attribute__((aligned(16))) bf16_t As[128 * 32];
  __shared__ __attribute__((aligned(16))) bf16_t Bs[128 * 32];
  const int tid = threadIdx.x;
  const int lane = tid & 63;
  const int wave = tid >> 6;
  const int bm = blockIdx.y * 128, bn = blockIdx.x * 128;
  const int wm = (wave >> 1) * 64, wn = (wave & 1) * 64;
  const int lr = lane & 15, quad = lane >> 4;

  floatx4 acc[4][4] = {};

  const int t0 = tid, t1 = tid + 256;
  const int r0 = t0 >> 2, c0 = (t0 & 3) * 8;
  const int r1 = t1 >> 2, c1 = (t1 & 3) * 8;

  const bf16_t* Ab = A + (size_t)bm * K;
  const bf16_t* Bb = Bm + (size_t)bn * K;

  for (int k0 = 0; k0 < K; k0 += 32) {
    __syncthreads();
    load_lds16(Ab + (size_t)r0 * K + k0 + c0, &As[t0 * 8]);
    load_lds16(Ab + (size_t)r1 * K + k0 + c1, &As[t1 * 8]);
    load_lds16(Bb + (size_t)r0 * K + k0 + c0, &Bs[t0 * 8]);
    load_lds16(Bb + (size_t)r1 * K + k0 + c1, &Bs[t1 * 8]);
    __syncthreads();

    short8 af[4], bfr[4];
#pragma unroll
    for (int i = 0; i < 4; i++) {
      af[i]  = *(const short8*)&As[(wm + i * 16 + lr) * 32 + quad * 8];
      bfr[i] = *(const short8*)&Bs[(wn + i * 16 + lr) * 32 + quad * 8];
    }
#pragma unroll
    for (int mi = 0; mi < 4; mi++)
#pragma unroll
      for (int ni = 0; ni < 4; ni++)
        acc[mi][ni] = __builtin_amdgcn_mfma_f32_16x16x32_bf16(af[mi], bfr[ni], acc[mi][ni], 0, 0, 0);
  }

#pragma unroll
  for (int mi = 0; mi < 4; mi++) {
    const int row = bm + wm + mi * 16 + quad * 4;
#pragma unroll
    for (int ni = 0; ni < 4; ni++) {
      const int col = bn + wn + ni * 16 + lr;
      float* cp = C + (size_t)row * N + col;
#pragma unroll
      for (int r = 0; r < 4; r++) cp[(size_t)r * N] = acc[mi][ni][r];
    }
  }
}

// ---------------- fused QKV GEMM + RoPE (fp16 table) + repack ----------------
__global__ __launch_bounds__(256, 4) void gemm_qkv(
    const bf16_t* __restrict__ A, const bf16_t* __restrict__ Bm,
    const unsigned* __restrict__ tab,
    bf16_t* __restrict__ q, bf16_t* __restrict__ k, bf16_t* __restrict__ vt) {
  const int K = 2048;
  __shared__ __attribute__((aligned(16))) bf16_t As[128 * 32];
  __shared__ __attribute__((aligned(16))) bf16_t Bs[128 * 32];
  __shared__ __attribute__((aligned(16))) bf16_t Ts[4][32 * 72];  // V transpose (2-pass)
  const int tid = threadIdx.x;
  const int lane = tid & 63;
  const int wave = tid >> 6;
  const int bm = blockIdx.y * 128, bn = blockIdx.x * 128;
  const int wm = (wave >> 1) * 64, wn = (wave & 1) * 64;
  const int lr = lane & 15, quad = lane >> 4;

  floatx4 acc[4][4] = {};

  const int t0 = tid, t1 = tid + 256;
  const int r0 = t0 >> 2, c0 = (t0 & 3) * 8;
  const int r1 = t1 >> 2, c1 = (t1 & 3) * 8;

  const bf16_t* Ab = A + (size_t)bm * K;
  const bf16_t* Bb = Bm + (size_t)bn * K;

  for (int k0 = 0; k0 < K; k0 += 32) {
    __syncthreads();
    load_lds16(Ab + (size_t)r0 * K + k0 + c0, &As[t0 * 8]);
    load_lds16(Ab + (size_t)r1 * K + k0 + c1, &As[t1 * 8]);
    load_lds16(Bb + (size_t)r0 * K + k0 + c0, &Bs[t0 * 8]);
    load_lds16(Bb + (size_t)r1 * K + k0 + c1, &Bs[t1 * 8]);
    __syncthreads();

    short8 af[4], bfr[4];
#pragma unroll
    for (int i = 0; i < 4; i++) {
      af[i]  = *(const short8*)&As[(wm + i * 16 + lr) * 32 + quad * 8];
      bfr[i] = *(const short8*)&Bs[(wn + i * 16 + lr) * 32 + quad * 8];
    }
#pragma unroll
    for (int mi = 0; mi < 4; mi++)
#pragma unroll
      for (int ni = 0; ni < 4; ni++)
        acc[mi][ni] = __builtin_amdgcn_mfma_f32_16x16x32_bf16(af[mi], bfr[ni], acc[mi][ni], 0, 0, 0);
  }

  const int f0 = bn + wn;              // wave-uniform feature base (multiple of 64)
  const int srow0 = bm + wm;
  const int bb = srow0 >> 11, s0 = srow0 & 2047;

  if (f0 < 2560) {                     // Q or K head: in-register rope
    const bool isq = (f0 < 2048);
    const float scale = isq ? 0.18033688011f : 1.0f;   // 0.125 * log2(e)
    bf16_t* dst = isq ? (q + (size_t)(bb * H_ + (f0 >> 6)) * S_ * HD_)
                      : (k + (size_t)(bb * KV_ + ((f0 - 2048) >> 6)) * S_ * HD_);
#pragma unroll
    for (int mi = 0; mi < 4; mi++) {
#pragma unroll
      for (int r = 0; r < 4; r++) {
        const int sr = s0 + mi * 16 + quad * 4 + r;
        const unsigned* tp = tab + (size_t)sr * HD_;
        bf16_t* drow = dst + (size_t)sr * HD_;
#pragma unroll
        for (int ni = 0; ni < 4; ni++) {
          const int d = ni * 16 + lr;
          const unsigned w = tp[d];
          __half2 h2; __builtin_memcpy(&h2, &w, 4);
          const float2 cf = __half22float2(h2);
          const float t = acc[mi][ni][r];
          const float oth = acc[mi][ni ^ 2][r];
          const float rot = (ni < 2) ? -oth : oth;   // d<32 iff ni<2
          drow[d] = f2bf((t * cf.x + rot * cf.y) * scale);
        }
      }
    }
  } else {                             // V head: 2-pass transpose via 9 KB/wave LDS
    const int hv = (f0 - 2560) >> 6;
    bf16_t* ts = Ts[wave];
    const int rl = lane >> 1, hf = lane & 1;
#pragma unroll
    for (int p = 0; p < 2; p++) {
#pragma unroll
      for (int nn = 0; nn < 2; nn++) {
        const int ni = 2 * p + nn;
#pragma unroll
        for (int mi = 0; mi < 4; mi++) {
          uint2 pw;
          pw.x = pk_bf16(acc[mi][ni][0], acc[mi][ni][1]);
          pw.y = pk_bf16(acc[mi][ni][2], acc[mi][ni][3]);
          *(uint2*)&ts[(nn * 16 + lr) * 72 + mi * 16 + quad * 4] = pw;
        }
      }
      // same-wave RAW/WAR: DS pipe is in-order per wave, compiler emits lgkmcnt
      bf16_t* vrow = vt + ((size_t)(bb * KV_ + hv) * HD_ + p * 32 + rl) * S_ + s0 + hf * 32;
#pragma unroll
      for (int j = 0; j < 4; j++)
        *(short8*)(vrow + j * 8) = *(const short8*)&ts[rl * 72 + hf * 32 + j * 8];
    }
  }
}

// ---------------- flash attention v2: 128-row blocks, 2 q-subtiles/wave ----------------
// Wave w owns q-rows {T*128+w*16, T*128+64+w*16}; K/V frags shared across both
// subtiles. Pair T with 15-T -> uniform 34 iters/block; grid 8x64 = 512 blocks.
__device__ __forceinline__ void stage64(const bf16_t* __restrict__ gbase, int rstride,
                                        bf16_t* lbuf, int wave, int lane) {
  const int sub = lane >> 3;
  const int sc  = lane & 7;
  const int gc  = sc ^ sub;
#pragma unroll
  for (int j = 0; j < 2; j++) {
    const int r = wave * 16 + j * 8 + sub;
    load_lds16(gbase + (size_t)r * rstride + gc * 8,
               lbuf + (wave * 128 + j * 64 + lane) * 8);
  }
}

// mask(optional) + online-softmax update + P-write for one 16x64 S^T tile
__device__ __forceinline__ void softmax_ps(
    floatx4* st, bool diag, int qg, int kk, float& m, float& l,
    floatx4* o, bf16_t* pl, int lr, int quad, int sw) {
  if (diag) {
#pragma unroll
    for (int t = 0; t < 4; t++)
#pragma unroll
      for (int r = 0; r < 4; r++) {
        const int kg = kk + t * 16 + quad * 4 + r;
        st[t][r] = (kg <= qg) ? st[t][r] : -1e30f;
      }
  }
  float mx = -3e30f;
#pragma unroll
  for (int t = 0; t < 4; t++)
#pragma unroll
    for (int r = 0; r < 4; r++) mx = fmaxf(mx, st[t][r]);
  mx = fmaxf(mx, __shfl_xor(mx, 16, 64));
  mx = fmaxf(mx, __shfl_xor(mx, 32, 64));
  const float mn = fmaxf(m, mx);
  float rs = 0.f;
#pragma unroll
  for (int t = 0; t < 4; t++)
#pragma unroll
    for (int r = 0; r < 4; r++) {
      const float p = fexp2(st[t][r] - mn);
      st[t][r] = p;
      rs += p;
    }
  rs += __shfl_xor(rs, 16, 64);
  rs += __shfl_xor(rs, 32, 64);
  if (__all(mn == m)) {
    l += rs;
  } else {
    const float a = fexp2(m - mn);
    l = l * a + rs;
    m = mn;
    const floatx4 a4 = { a, a, a, a };
#pragma unroll
    for (int dt = 0; dt < 4; dt++) o[dt] *= a4;
  }
#pragma unroll
  for (int t = 0; t < 4; t++) {
    uint2 pw;
    pw.x = pk_bf16(st[t][0], st[t][1]);
    pw.y = pk_bf16(st[t][2], st[t][3]);
    *(uint2*)&pl[lr * 64 + (((2 * t + (quad >> 1)) ^ sw) * 8) + (quad & 1) * 4] = pw;
  }
}

__device__ __forceinline__ void store_o(
    const floatx4* o, float l, bf16_t* __restrict__ O,
    int b, int h, int q0, int lr, int quad) {
  const float linv = 1.f / l;
  const floatx4 lv = { linv, linv, linv, linv };
  bf16_t* ob = O + ((size_t)b * S_ + q0 + lr) * (H_ * HD_) + h * HD_ + quad * 4;
#pragma unroll
  for (int dt = 0; dt < 4; dt++) {
    const floatx4 ov = o[dt] * lv;
    uint2 pw;
    pw.x = pk_bf16(ov[0], ov[1]);
    pw.y = pk_bf16(ov[2], ov[3]);
    *(uint2*)(ob + dt * 16) = pw;
  }
}

__device__ __forceinline__ void attn_half(
    const bf16_t* __restrict__ Q, const bf16_t* __restrict__ kb,
    const bf16_t* __restrict__ vb, bf16_t* __restrict__ O,
    bf16_t* Ks, bf16_t* Vs, bf16_t* pla, bf16_t* plb,
    int bh, int T, int wave, int lr, int quad) {
  const int b = bh >> 5, h = bh & 31;
  const int lane = quad * 16 + lr;
  const int sw = lr & 7;
  const int qa0 = T * 128 + wave * 16;
  const int qb0 = qa0 + 64;
  const bf16_t* qpa = Q + ((size_t)bh * S_ + qa0) * HD_;
  const short8 qfa0 = *(const short8*)(qpa + lr * HD_ + quad * 8);
  const short8 qfa1 = *(const short8*)(qpa + lr * HD_ + 32 + quad * 8);
  const short8 qfb0 = *(const short8*)(qpa + (64 + lr) * HD_ + quad * 8);
  const short8 qfb1 = *(const short8*)(qpa + (64 + lr) * HD_ + 32 + quad * 8);

  floatx4 oa[4] = {}, ob[4] = {};
  float ma = -1e30f, la = 0.f, mb = -1e30f, lb = 0.f;
  const int qga = qa0 + lr, qgb = qb0 + lr;
  const int nt = 2 * T + 2;          // uniform across the block's 4 waves

  stage64(kb, HD_, Ks, wave, lane);
  stage64(vb, S_, Vs, wave, lane);

  for (int kt = 0; kt < nt; kt++) {
    const int kk = kt * 64;
    bf16_t* Kc = Ks + (kt & 1) * 4096;
    bf16_t* Vc = Vs + (kt & 1) * 4096;
    __syncthreads();
    if (kt + 1 < nt) {
      stage64(kb + (size_t)(kk + 64) * HD_, HD_, Ks + ((kt + 1) & 1) * 4096, wave, lane);
      stage64(vb + (kk + 64), S_, Vs + ((kt + 1) & 1) * 4096, wave, lane);
    }
    const bool doA  = (kt <= 2 * T);   // a's last active chunk is kt == 2T
    const bool dgA  = (kt == 2 * T);
    const bool dgB  = (kt == nt - 1);

    floatx4 sta[4] = {}, stb[4] = {};
#pragma unroll
    for (int t = 0; t < 4; t++) {
      const int R = t * 16 + lr;
      const short8 kf0 = *(const short8*)&Kc[R * 64 + ((quad ^ sw) * 8)];
      const short8 kf1 = *(const short8*)&Kc[R * 64 + (((4 + quad) ^ sw) * 8)];
      if (doA) {
        sta[t] = __builtin_amdgcn_mfma_f32_16x16x32_bf16(kf0, qfa0, sta[t], 0, 0, 0);
        sta[t] = __builtin_amdgcn_mfma_f32_16x16x32_bf16(kf1, qfa1, sta[t], 0, 0, 0);
      }
      stb[t] = __builtin_amdgcn_mfma_f32_16x16x32_bf16(kf0, qfb0, stb[t], 0, 0, 0);
      stb[t] = __builtin_amdgcn_mfma_f32_16x16x32_bf16(kf1, qfb1, stb[t], 0, 0, 0);
    }
    if (doA) softmax_ps(sta, dgA, qga, kk, ma, la, oa, pla, lr, quad, sw);
    softmax_ps(stb, dgB, qgb, kk, mb, lb, ob, plb, lr, quad, sw);

    short8 pfa0, pfa1;
    if (doA) {
      pfa0 = *(const short8*)&pla[lr * 64 + ((quad ^ sw) * 8)];
      pfa1 = *(const short8*)&pla[lr * 64 + (((4 + quad) ^ sw) * 8)];
    }
    const short8 pfb0 = *(const short8*)&plb[lr * 64 + ((quad ^ sw) * 8)];
    const short8 pfb1 = *(const short8*)&plb[lr * 64 + (((4 + quad) ^ sw) * 8)];
#pragma unroll
    for (int dt = 0; dt < 4; dt++) {
      const int Rv = dt * 16 + lr;
      const short8 vf0 = *(const short8*)&Vc[Rv * 64 + ((quad ^ sw) * 8)];
      const short8 vf1 = *(const short8*)&Vc[Rv * 64 + (((4 + quad) ^ sw) * 8)];
      if (doA) {
        oa[dt] = __builtin_amdgcn_mfma_f32_16x16x32_bf16(vf0, pfa0, oa[dt], 0, 0, 0);
        oa[dt] = __builtin_amdgcn_mfma_f32_16x16x32_bf16(vf1, pfa1, oa[dt], 0, 0, 0);
      }
      ob[dt] = __builtin_amdgcn_mfma_f32_16x16x32_bf16(vf0, pfb0, ob[dt], 0, 0, 0);
      ob[dt] = __builtin_amdgcn_mfma_f32_16x16x32_bf16(vf1, pfb1, ob[dt], 0, 0, 0);
    }
  }

  store_o(oa, la, O, b, h, qa0, lr, quad);
  store_o(ob, lb, O, b, h, qb0, lr, quad);
}

__global__ __launch_bounds__(256, 2) void flash_attn(
    const bf16_t* __restrict__ Q,   // [B*H, S, 64] (pre-scaled by 0.125*log2e)
    const bf16_t* __restrict__ Kc,  // [B*KV, S, 64]
    const bf16_t* __restrict__ Vt,  // [B*KV, 64, S]
    bf16_t* __restrict__ O) {       // [B, S, H*64]
  __shared__ __attribute__((aligned(16))) bf16_t Ks[2 * 4096];  // 16 KB
  __shared__ __attribute__((aligned(16))) bf16_t Vs[2 * 4096];  // 16 KB
  __shared__ __attribute__((aligned(16))) bf16_t Pl[8192];      // 16 KB -> 48 KB total
  const int bh = blockIdx.y;
  const int b = bh >> 5, h = bh & 31;
  const int kvh = b * KV_ + (h >> 2);
  const int wave = threadIdx.x >> 6, lane = threadIdx.x & 63;
  const int lr = lane & 15, quad = lane >> 4;

  const bf16_t* kb = Kc + (size_t)kvh * S_ * HD_;
  const bf16_t* vb = Vt + (size_t)kvh * HD_ * S_;
  bf16_t* pla = Pl + wave * 2048;
  bf16_t* plb = pla + 1024;

  const int ta = blockIdx.x;        // 0..7  (light half)
  const int tb = 15 - blockIdx.x;   // heavy half; total iters uniform (34)
  attn_half(Q, kb, vb, O, Ks, Vs, pla, plb, bh, ta, wave, lr, quad);
  __syncthreads();                  // half-A readers done before half-B staging
  attn_half(Q, kb, vb, O, Ks, Vs, pla, plb, bh, tb, wave, lr, quad);
}

extern "C" void kernel_launch(void* const* d_in, const int* in_sizes, int n_in,
                              void* d_out, int out_size, void* d_ws, size_t ws_size,
                              hipStream_t stream) {
  const float* x    = (const float*)d_in[0];
  const float* cs   = (const float*)d_in[1];
  const float* sn   = (const float*)d_in[2];
  const float* wqkv = (const float*)d_in[3];
  const float* wout = (const float*)d_in[4];
  float* out = (float*)d_out;

  char* ws = (char*)d_ws;
  bf16_t*  xb    = (bf16_t*)(ws);                 // 16,777,216 B
  bf16_t*  wqkvb = (bf16_t*)(ws + 16777216);      // 12,582,912 B
  bf16_t*  woutb = (bf16_t*)(ws + 29360128);      //  8,388,608 B
  bf16_t*  qb    = (bf16_t*)(ws + 37748736);      // 16,777,216 B
  bf16_t*  kb    = (bf16_t*)(ws + 54525952);      //  4,194,304 B
  bf16_t*  vtb   = (bf16_t*)(ws + 58720256);      //  4,194,304 B
  bf16_t*  attnb = (bf16_t*)(ws + 62914560);      // 16,777,216 B
  unsigned* tab  = (unsigned*)(ws + 79691776);    //    524,288 B (total ~80 MB)

  prep<<<18944, 256, 0, stream>>>(x, xb, wqkv, wqkvb, wout, woutb, cs, sn, tab);
  gemm_qkv<<<dim3(24, 32), 256, 0, stream>>>(xb, wqkvb, tab, qb, kb, vtb);
  flash_attn<<<dim3(8, 64), 256, 0, stream>>>(qb, kb, vtb, attnb);
  gemm_bt<<<dim3(16, 32), 256, 0, stream>>>(attnb, woutb, out, 4096, 2048, 2048);
}